// Round 2
// baseline (244.642 us; speedup 1.0000x reference)
//
#include <hip/hip_runtime.h>

// ---------------------------------------------------------------------------
// Fused causal MHA:  out = attn(x@Wqkv+b) @ Wproj + bproj
// B=2, L=2048, D=1024, H=16, DH=64
// Device buffers may be f32 or bf16 -- detected at runtime from x's bit
// patterns; all compute is bf16 MFMA internally.
// ---------------------------------------------------------------------------

typedef __bf16 bf16x8 __attribute__((ext_vector_type(8)));
typedef float  f32x4  __attribute__((ext_vector_type(4)));
typedef unsigned short bhalf;
typedef unsigned int   uint32;

#define B_  2
#define L_  2048
#define D_  1024
#define H_  16
#define DH_ 64

#define GPTR(p) ((const __attribute__((address_space(1))) void*)(p))
#define SPTR(p) ((__attribute__((address_space(3))) void*)(p))

static __device__ __forceinline__ float bf2f(bhalf u) {
    union { uint32 u; float f; } x; x.u = ((uint32)u) << 16; return x.f;
}
static __device__ __forceinline__ bhalf f2bf(float f) {
    union { float f; uint32 u; } x; x.f = f;
    uint32 r = x.u + 0x7FFFu + ((x.u >> 16) & 1u);   // RNE
    return (bhalf)(r >> 16);
}

// ---------------------------------------------------------------------------
// dtype detection: x ~ N(0,1). If words are f32, their low 16 bits viewed as
// bf16 have ~uniform-random exponents (garbage); if genuine bf16, exponents
// cluster near 0x7F. flag: 0 = f32 buffers, 1 = bf16 buffers.
// ---------------------------------------------------------------------------
__global__ void detect_dtype(const uint32* __restrict__ xw, int* __restrict__ flag) {
    int t = threadIdx.x;                     // 64 threads
    uint32 w = xw[t];
    uint32 e = (w >> 7) & 0xFFu;             // exponent of low-half bf16
    int g = (e < 0x6Fu || e > 0x84u) ? 1 : 0;  // |v|<2^-16 or |v|>32 => garbage
#pragma unroll
    for (int off = 32; off; off >>= 1) g += __shfl_xor(g, off);
    if (t == 0) *flag = (g > 16) ? 0 : 1;
}

// ---------------------------------------------------------------------------
// convert x (f32 or bf16) -> bf16, 4 elems/thread
// ---------------------------------------------------------------------------
__global__ void conv_bf16(const void* __restrict__ in, bhalf* __restrict__ out,
                          int n4, const int* __restrict__ flag) {
    const bool isb = (*flag != 0);
    for (int i = blockIdx.x * blockDim.x + threadIdx.x; i < n4;
         i += gridDim.x * blockDim.x) {
        if (isb) {
            ((uint2*)out)[i] = ((const uint2*)in)[i];
        } else {
            float4 v = ((const float4*)in)[i];
            uint2 o;
            o.x = (uint32)f2bf(v.x) | ((uint32)f2bf(v.y) << 16);
            o.y = (uint32)f2bf(v.z) | ((uint32)f2bf(v.w) << 16);
            ((uint2*)out)[i] = o;
        }
    }
}

// ---------------------------------------------------------------------------
// transpose + convert: in [R][C] (f32 or bf16) -> out [C][R] bf16
// ---------------------------------------------------------------------------
__global__ void tr_conv(const void* __restrict__ in, bhalf* __restrict__ out,
                        int R, int C, const int* __restrict__ flag) {
    __shared__ bhalf t[32][33];
    const bool isb = (*flag != 0);
    int bx = blockIdx.x, by = blockIdx.y;
    int tx = threadIdx.x, ty = threadIdx.y;   // (32, 8)
#pragma unroll
    for (int i = 0; i < 32; i += 8) {
        size_t idx = (size_t)(by * 32 + ty + i) * C + bx * 32 + tx;
        t[ty + i][tx] = isb ? ((const bhalf*)in)[idx]
                            : f2bf(((const float*)in)[idx]);
    }
    __syncthreads();
#pragma unroll
    for (int i = 0; i < 32; i += 8)
        out[(size_t)(bx * 32 + ty + i) * R + by * 32 + tx] = t[tx][ty + i];
}

// ---------------------------------------------------------------------------
// GEMM  C[M][N] = A[M][K] @ Bt[N][K]^T + bias[N]     (A, Bt are bf16)
// 128x128 tile, BK=32, 256 threads = 4 waves each 64x64.
// MODE 0: write C row-major (f32 or bf16 per flag) to C0.
// MODE 1: QKV scatter: Q,K -> [B,H,L,DH] bf16, V -> Vt [B,H,DH,L] bf16.
// ---------------------------------------------------------------------------
template <int MODE>
__global__ __launch_bounds__(256) void gemm_bt(
        const bhalf* __restrict__ A, const bhalf* __restrict__ Bt,
        const void* __restrict__ bias,
        void* __restrict__ C0, bhalf* __restrict__ Qb,
        bhalf* __restrict__ Kb, bhalf* __restrict__ Vtb,
        int M, int N, int K, const int* __restrict__ flag) {
    __shared__ bhalf As[128 * 32];
    __shared__ bhalf Bs[128 * 32];
    const bool isb = (*flag != 0);
    const int tid  = threadIdx.x;
    const int w    = tid >> 6, lane = tid & 63;
    const int g    = lane >> 4, cl = lane & 15;
    const int m0   = blockIdx.y * 128, n0 = blockIdx.x * 128;
    const int wr   = (w >> 1) * 64, wc = (w & 1) * 64;

    f32x4 acc[4][4] = {};

    const bhalf* a0 = A  + (size_t)m0 * K;
    const bhalf* b0 = Bt + (size_t)n0 * K;

    for (int kk = 0; kk < K; kk += 32) {
        __syncthreads();
        // stage A,B tiles (chunk-XOR-swizzled source, linear LDS dest)
#pragma unroll
        for (int r = 0; r < 2; r++) {
            int c = r * 256 + tid;
            int row = c >> 2, p = c & 3;
            int gch = p ^ (row & 3);
            __builtin_amdgcn_global_load_lds(
                GPTR(a0 + (size_t)row * K + kk + gch * 8),
                SPTR(As + (r * 256 + w * 64) * 8), 16, 0, 0);
            __builtin_amdgcn_global_load_lds(
                GPTR(b0 + (size_t)row * K + kk + gch * 8),
                SPTR(Bs + (r * 256 + w * 64) * 8), 16, 0, 0);
        }
        __syncthreads();

        bf16x8 af[4], bf[4];
#pragma unroll
        for (int i = 0; i < 4; i++) {
            int ra = wr + i * 16 + cl;
            af[i] = *(const bf16x8*)(As + ra * 32 + ((g ^ (ra & 3)) * 8));
            int rb = wc + i * 16 + cl;
            bf[i] = *(const bf16x8*)(Bs + rb * 32 + ((g ^ (rb & 3)) * 8));
        }
#pragma unroll
        for (int i = 0; i < 4; i++)
#pragma unroll
            for (int j = 0; j < 4; j++)
                acc[i][j] = __builtin_amdgcn_mfma_f32_16x16x32_bf16(
                    af[i], bf[j], acc[i][j], 0, 0, 0);
    }

    // epilogue: C/D layout col = lane&15, row = (lane>>4)*4 + reg
#pragma unroll
    for (int i = 0; i < 4; i++) {
#pragma unroll
        for (int j = 0; j < 4; j++) {
            int nn = n0 + wc + j * 16 + cl;
            float bv = isb ? bf2f(((const bhalf*)bias)[nn])
                           : ((const float*)bias)[nn];
#pragma unroll
            for (int r = 0; r < 4; r++) {
                int mm = m0 + wr + i * 16 + g * 4 + r;
                float v = acc[i][j][r] + bv;
                if (MODE == 0) {
                    if (isb) ((bhalf*)C0)[(size_t)mm * N + nn] = f2bf(v);
                    else     ((float*)C0)[(size_t)mm * N + nn] = v;
                } else {
                    bhalf o = f2bf(v);
                    int b = mm >> 11, l = mm & 2047;
                    int three = nn >> 10, rem = nn & 1023;
                    int h = rem >> 6, dh = rem & 63;
                    size_t bh = (size_t)(b * 16 + h);
                    if (three == 0)      Qb [(bh * 2048 + l) * 64 + dh] = o;
                    else if (three == 1) Kb [(bh * 2048 + l) * 64 + dh] = o;
                    else                 Vtb[(bh * 64 + dh) * 2048 + l] = o;
                }
            }
        }
    }
}

// ---------------------------------------------------------------------------
// Causal flash attention. grid (L/128, B*H), 256 threads = 4 waves.
// Wave w owns q-rows [qt*128 + w*32, +32). K-tile = 128.
// Q [B,H,L,DH], K [B,H,L,DH], Vt [B,H,DH,L]; O -> [B,L,D] bf16.
// ---------------------------------------------------------------------------
__global__ __launch_bounds__(256) void attn_fwd(
        const bhalf* __restrict__ Qb, const bhalf* __restrict__ Kb,
        const bhalf* __restrict__ Vtb, bhalf* __restrict__ Ob) {
    __shared__ bhalf Ks[128 * 64];    // [krow][d]   chunk-swizzled by row&7
    __shared__ bhalf Vs[64 * 128];    // [d][kcol]   chunk-swizzled by row&15
    __shared__ bhalf Ps[4][32 * 128]; // per-wave P, chunk-swizzled by row&15

    const int qt = blockIdx.x;
    const int bh = blockIdx.y;
    const int tid = threadIdx.x;
    const int w = tid >> 6, lane = tid & 63;
    const int g = lane >> 4, cl = lane & 15;

    const bhalf* Q  = Qb  + (size_t)bh * L_ * DH_;
    const bhalf* Kp = Kb  + (size_t)bh * L_ * DH_;
    const bhalf* Vt = Vtb + (size_t)bh * DH_ * L_;

    const int q0 = qt * 128 + w * 32;

    // Q fragments held in registers for the whole block
    bf16x8 qf[2][2];
#pragma unroll
    for (int fi = 0; fi < 2; fi++)
#pragma unroll
        for (int ks = 0; ks < 2; ks++)
            qf[fi][ks] = *(const bf16x8*)(Q + (size_t)(q0 + fi * 16 + cl) * 64
                                            + ks * 32 + g * 8);

    f32x4 oacc[2][4] = {};
    float mrow[2][4], lrow[2][4];
#pragma unroll
    for (int fi = 0; fi < 2; fi++)
#pragma unroll
        for (int r = 0; r < 4; r++) { mrow[fi][r] = -__builtin_inff(); lrow[fi][r] = 0.f; }

    for (int kt = 0; kt <= qt; ++kt) {
        __syncthreads();
        // stage K tile [128][64]
#pragma unroll
        for (int r = 0; r < 4; r++) {
            int c = r * 256 + tid;
            int row = c >> 3, p = c & 7;
            int gch = p ^ (row & 7);
            __builtin_amdgcn_global_load_lds(
                GPTR(Kp + (size_t)(kt * 128 + row) * 64 + gch * 8),
                SPTR(Ks + (r * 256 + w * 64) * 8), 16, 0, 0);
        }
        // stage Vt tile [64][128]
#pragma unroll
        for (int r = 0; r < 4; r++) {
            int c = r * 256 + tid;
            int row = c >> 4, p = c & 15;
            int gch = p ^ (row & 15);
            __builtin_amdgcn_global_load_lds(
                GPTR(Vt + (size_t)row * L_ + kt * 128 + gch * 8),
                SPTR(Vs + (r * 256 + w * 64) * 8), 16, 0, 0);
        }
        __syncthreads();

        // S = Q @ K^T for this wave's 32 q-rows x 128 k-cols
        f32x4 s[2][8] = {};
#pragma unroll
        for (int ks = 0; ks < 2; ks++) {
            bf16x8 kf[8];
#pragma unroll
            for (int j = 0; j < 8; j++) {
                int row = j * 16 + cl;
                int ch  = ks * 4 + g;
                kf[j] = *(const bf16x8*)(Ks + row * 64 + ((ch ^ (row & 7)) * 8));
            }
#pragma unroll
            for (int fi = 0; fi < 2; fi++)
#pragma unroll
                for (int j = 0; j < 8; j++)
                    s[fi][j] = __builtin_amdgcn_mfma_f32_16x16x32_bf16(
                        qf[fi][ks], kf[j], s[fi][j], 0, 0, 0);
        }

        // online softmax (16-lane shuffle reduce), write P to per-wave LDS
#pragma unroll
        for (int fi = 0; fi < 2; fi++) {
#pragma unroll
            for (int r = 0; r < 4; r++) {
                int rowAbs = qt * 128 + w * 32 + fi * 16 + g * 4 + r;
                float sv[8];
                float mx = -__builtin_inff();
#pragma unroll
                for (int j = 0; j < 8; j++) {
                    int colAbs = kt * 128 + j * 16 + cl;
                    float v = s[fi][j][r] * 0.125f;
                    v = (colAbs > rowAbs) ? -__builtin_inff() : v;
                    sv[j] = v;
                    mx = fmaxf(mx, v);
                }
#pragma unroll
                for (int off = 1; off < 16; off <<= 1)
                    mx = fmaxf(mx, __shfl_xor(mx, off));
                float mnew  = fmaxf(mrow[fi][r], mx);
                float alpha = __expf(mrow[fi][r] - mnew);
                mrow[fi][r] = mnew;
                float ls = 0.f;
#pragma unroll
                for (int j = 0; j < 8; j++) {
                    float p = __expf(sv[j] - mnew);
                    sv[j] = p;
                    ls += p;
                }
#pragma unroll
                for (int off = 1; off < 16; off <<= 1)
                    ls += __shfl_xor(ls, off);
                lrow[fi][r] = lrow[fi][r] * alpha + ls;
#pragma unroll
                for (int dj = 0; dj < 4; dj++) oacc[fi][dj][r] *= alpha;

                int prow = fi * 16 + g * 4 + r;
#pragma unroll
                for (int j = 0; j < 8; j++) {
                    int col = j * 16 + cl;
                    int ch  = col >> 3;
                    Ps[w][prow * 128 + ((ch ^ (prow & 15)) * 8) + (col & 7)] = f2bf(sv[j]);
                }
            }
        }
        __syncthreads();

        // O += P @ Vt^T  (contraction over 128 k, 4 k-steps of 32)
#pragma unroll
        for (int ks2 = 0; ks2 < 4; ks2++) {
            bf16x8 pf[2], vf[4];
#pragma unroll
            for (int fi = 0; fi < 2; fi++) {
                int prow = fi * 16 + cl;
                int ch   = ks2 * 4 + g;
                pf[fi] = *(const bf16x8*)(&Ps[w][prow * 128 + ((ch ^ (prow & 15)) * 8)]);
            }
#pragma unroll
            for (int dj = 0; dj < 4; dj++) {
                int vrow = dj * 16 + cl;
                int ch   = ks2 * 4 + g;
                vf[dj] = *(const bf16x8*)(Vs + vrow * 128 + ((ch ^ (vrow & 15)) * 8));
            }
#pragma unroll
            for (int fi = 0; fi < 2; fi++)
#pragma unroll
                for (int dj = 0; dj < 4; dj++)
                    oacc[fi][dj] = __builtin_amdgcn_mfma_f32_16x16x32_bf16(
                        pf[fi], vf[dj], oacc[fi][dj], 0, 0, 0);
        }
    }

    // epilogue: divide by softmax denom (+1e-6 per reference), write O [B,L,D]
    const int b = bh >> 4, h = bh & 15;
#pragma unroll
    for (int fi = 0; fi < 2; fi++) {
#pragma unroll
        for (int r = 0; r < 4; r++) {
            float inv = 1.f / (lrow[fi][r] + 1e-6f);
            int row = q0 + fi * 16 + g * 4 + r;
#pragma unroll
            for (int dj = 0; dj < 4; dj++) {
                int col = dj * 16 + cl;
                Ob[((size_t)b * L_ + row) * D_ + h * 64 + col] =
                    f2bf(oacc[fi][dj][r] * inv);
            }
        }
    }
}

// ---------------------------------------------------------------------------
extern "C" void kernel_launch(void* const* d_in, const int* in_sizes, int n_in,
                              void* d_out, int out_size, void* d_ws, size_t ws_size,
                              hipStream_t stream) {
    const void* x     = d_in[0];   // [B,L,D]     f32 or bf16
    const void* Wqkv  = d_in[1];   // [D, 3D]
    const void* bqkv  = d_in[2];   // [3D]
    const void* Wproj = d_in[3];   // [D, D]
    const void* bproj = d_in[4];   // [D]

    char* ws = (char*)d_ws;
    const size_t SZ_FLG = 256;
    const size_t SZ_WQT = (size_t)3 * D_ * D_ * 2;        //  6 MB  Wqkv^T [3D][D]
    const size_t SZ_WPT = (size_t)D_ * D_ * 2;            //  2 MB  Wproj^T [D][D]
    const size_t SZ_X   = (size_t)B_ * L_ * D_ * 2;       //  8 MB  x bf16
    const size_t SZ_BUF = (size_t)B_ * H_ * L_ * DH_ * 2; //  8 MB  each

    int*   flag = (int*)ws;
    bhalf* Wq_t = (bhalf*)(ws + SZ_FLG);
    bhalf* Wp_t = (bhalf*)(ws + SZ_FLG + SZ_WQT);
    bhalf* Xb   = (bhalf*)(ws + SZ_FLG + SZ_WQT + SZ_WPT);
    bhalf* Qbuf = (bhalf*)(ws + SZ_FLG + SZ_WQT + SZ_WPT + SZ_X);
    bhalf* Kbuf = (bhalf*)(ws + SZ_FLG + SZ_WQT + SZ_WPT + SZ_X + SZ_BUF);
    bhalf* Vtbf = (bhalf*)(ws + SZ_FLG + SZ_WQT + SZ_WPT + SZ_X + 2 * SZ_BUF);
    bhalf* Obuf = (bhalf*)(ws + SZ_FLG + SZ_WQT + SZ_WPT + SZ_X + 3 * SZ_BUF);

    const int M = B_ * L_;   // 4096

    // 0. runtime dtype detection from x's bit patterns
    detect_dtype<<<1, 64, 0, stream>>>((const uint32*)x, flag);

    // 1. canonicalize inputs to bf16 workspace
    conv_bf16<<<2048, 256, 0, stream>>>(x, Xb, (B_ * L_ * D_) / 4, flag);
    tr_conv<<<dim3(3 * D_ / 32, D_ / 32), dim3(32, 8), 0, stream>>>(
        Wqkv, Wq_t, D_, 3 * D_, flag);
    tr_conv<<<dim3(D_ / 32, D_ / 32), dim3(32, 8), 0, stream>>>(
        Wproj, Wp_t, D_, D_, flag);

    // 2. QKV projection + scatter to Q,K [B,H,L,DH] and Vt [B,H,DH,L]
    gemm_bt<1><<<dim3(3 * D_ / 128, M / 128), 256, 0, stream>>>(
        Xb, Wq_t, bqkv, nullptr, Qbuf, Kbuf, Vtbf, M, 3 * D_, D_, flag);

    // 3. causal flash attention -> Obuf [B,L,D] bf16
    attn_fwd<<<dim3(L_ / 128, B_ * H_), 256, 0, stream>>>(Qbuf, Kbuf, Vtbf, Obuf);

    // 4. output projection -> d_out (f32 or bf16 per flag)
    gemm_bt<0><<<dim3(D_ / 128, M / 128), 256, 0, stream>>>(
        Obuf, Wp_t, bproj, d_out, nullptr, nullptr, nullptr, M, D_, D_, flag);
}

// Round 3
// 158.838 us; speedup vs baseline: 1.5402x; 1.5402x over previous
//
#include <hip/hip_runtime.h>

// ---------------------------------------------------------------------------
// Fused causal MHA:  out = attn(x@Wqkv+b) @ Wproj + bproj
// B=2, L=2048, D=1024, H=16, DH=64
// Device buffers may be f32 or bf16 -- detected at runtime from x's bit
// patterns; all compute is bf16 MFMA internally.
// ---------------------------------------------------------------------------

typedef __bf16 bf16x8 __attribute__((ext_vector_type(8)));
typedef float  f32x4  __attribute__((ext_vector_type(4)));
typedef unsigned short bhalf;
typedef unsigned int   uint32;

#define B_  2
#define L_  2048
#define D_  1024
#define H_  16
#define DH_ 64

#define GPTR(p) ((const __attribute__((address_space(1))) void*)(p))
#define SPTR(p) ((__attribute__((address_space(3))) void*)(p))

static __device__ __forceinline__ float bf2f(bhalf u) {
    union { uint32 u; float f; } x; x.u = ((uint32)u) << 16; return x.f;
}
static __device__ __forceinline__ bhalf f2bf(float f) {
    union { float f; uint32 u; } x; x.f = f;
    uint32 r = x.u + 0x7FFFu + ((x.u >> 16) & 1u);   // RNE
    return (bhalf)(r >> 16);
}

// ---------------------------------------------------------------------------
// dtype detection: x ~ N(0,1). If words are f32, their low 16 bits viewed as
// bf16 have ~uniform-random exponents (garbage); if genuine bf16, exponents
// cluster near 0x7F. flag: 0 = f32 buffers, 1 = bf16 buffers.
// ---------------------------------------------------------------------------
__global__ void detect_dtype(const uint32* __restrict__ xw, int* __restrict__ flag) {
    int t = threadIdx.x;                     // 64 threads
    uint32 w = xw[t];
    uint32 e = (w >> 7) & 0xFFu;             // exponent of low-half bf16
    int g = (e < 0x6Fu || e > 0x84u) ? 1 : 0;  // |v|<2^-16 or |v|>32 => garbage
#pragma unroll
    for (int off = 32; off; off >>= 1) g += __shfl_xor(g, off);
    if (t == 0) *flag = (g > 16) ? 0 : 1;
}

// ---------------------------------------------------------------------------
// convert x (f32 or bf16) -> bf16, 4 elems/thread
// ---------------------------------------------------------------------------
__global__ void conv_bf16(const void* __restrict__ in, bhalf* __restrict__ out,
                          int n4, const int* __restrict__ flag) {
    const bool isb = (*flag != 0);
    for (int i = blockIdx.x * blockDim.x + threadIdx.x; i < n4;
         i += gridDim.x * blockDim.x) {
        if (isb) {
            ((uint2*)out)[i] = ((const uint2*)in)[i];
        } else {
            float4 v = ((const float4*)in)[i];
            uint2 o;
            o.x = (uint32)f2bf(v.x) | ((uint32)f2bf(v.y) << 16);
            o.y = (uint32)f2bf(v.z) | ((uint32)f2bf(v.w) << 16);
            ((uint2*)out)[i] = o;
        }
    }
}

// ---------------------------------------------------------------------------
// transpose + convert: in [R][C] (f32 or bf16) -> out [C][R] bf16
// ---------------------------------------------------------------------------
__global__ void tr_conv(const void* __restrict__ in, bhalf* __restrict__ out,
                        int R, int C, const int* __restrict__ flag) {
    __shared__ bhalf t[32][33];
    const bool isb = (*flag != 0);
    int bx = blockIdx.x, by = blockIdx.y;
    int tx = threadIdx.x, ty = threadIdx.y;   // (32, 8)
#pragma unroll
    for (int i = 0; i < 32; i += 8) {
        size_t idx = (size_t)(by * 32 + ty + i) * C + bx * 32 + tx;
        t[ty + i][tx] = isb ? ((const bhalf*)in)[idx]
                            : f2bf(((const float*)in)[idx]);
    }
    __syncthreads();
#pragma unroll
    for (int i = 0; i < 32; i += 8)
        out[(size_t)(bx * 32 + ty + i) * R + by * 32 + tx] = t[tx][ty + i];
}

// ---------------------------------------------------------------------------
// GEMM  C[M][N] = A[M][K] @ Bt[N][K]^T + bias[N]     (A, Bt are bf16)
// 128x128 tile, BK=32, 256 threads = 4 waves each 64x64.
// MODE 0: write C row-major (f32 or bf16 per flag) to C0.
// MODE 1: QKV scatter: Q,K -> [B,H,L,DH] bf16, V -> Vt [B,H,DH,L] bf16.
// ---------------------------------------------------------------------------
template <int MODE>
__global__ __launch_bounds__(256) void gemm_bt(
        const bhalf* __restrict__ A, const bhalf* __restrict__ Bt,
        const void* __restrict__ bias,
        void* __restrict__ C0, bhalf* __restrict__ Qb,
        bhalf* __restrict__ Kb, bhalf* __restrict__ Vtb,
        int M, int N, int K, const int* __restrict__ flag) {
    __shared__ bhalf As[128 * 32];
    __shared__ bhalf Bs[128 * 32];
    const bool isb = (*flag != 0);
    const int tid  = threadIdx.x;
    const int w    = tid >> 6, lane = tid & 63;
    const int g    = lane >> 4, cl = lane & 15;
    const int m0   = blockIdx.y * 128, n0 = blockIdx.x * 128;
    const int wr   = (w >> 1) * 64, wc = (w & 1) * 64;

    f32x4 acc[4][4] = {};

    const bhalf* a0 = A  + (size_t)m0 * K;
    const bhalf* b0 = Bt + (size_t)n0 * K;

    for (int kk = 0; kk < K; kk += 32) {
        __syncthreads();
        // stage A,B tiles (chunk-XOR-swizzled source, linear LDS dest)
#pragma unroll
        for (int r = 0; r < 2; r++) {
            int c = r * 256 + tid;
            int row = c >> 2, p = c & 3;
            int gch = p ^ (row & 3);
            __builtin_amdgcn_global_load_lds(
                GPTR(a0 + (size_t)row * K + kk + gch * 8),
                SPTR(As + (r * 256 + w * 64) * 8), 16, 0, 0);
            __builtin_amdgcn_global_load_lds(
                GPTR(b0 + (size_t)row * K + kk + gch * 8),
                SPTR(Bs + (r * 256 + w * 64) * 8), 16, 0, 0);
        }
        __syncthreads();

        bf16x8 af[4], bf[4];
#pragma unroll
        for (int i = 0; i < 4; i++) {
            int ra = wr + i * 16 + cl;
            af[i] = *(const bf16x8*)(As + ra * 32 + ((g ^ (ra & 3)) * 8));
            int rb = wc + i * 16 + cl;
            bf[i] = *(const bf16x8*)(Bs + rb * 32 + ((g ^ (rb & 3)) * 8));
        }
#pragma unroll
        for (int i = 0; i < 4; i++)
#pragma unroll
            for (int j = 0; j < 4; j++)
                acc[i][j] = __builtin_amdgcn_mfma_f32_16x16x32_bf16(
                    af[i], bf[j], acc[i][j], 0, 0, 0);
    }

    // epilogue: C/D layout col = lane&15, row = (lane>>4)*4 + reg
#pragma unroll
    for (int i = 0; i < 4; i++) {
#pragma unroll
        for (int j = 0; j < 4; j++) {
            int nn = n0 + wc + j * 16 + cl;
            float bv = isb ? bf2f(((const bhalf*)bias)[nn])
                           : ((const float*)bias)[nn];
#pragma unroll
            for (int r = 0; r < 4; r++) {
                int mm = m0 + wr + i * 16 + g * 4 + r;
                float v = acc[i][j][r] + bv;
                if (MODE == 0) {
                    if (isb) ((bhalf*)C0)[(size_t)mm * N + nn] = f2bf(v);
                    else     ((float*)C0)[(size_t)mm * N + nn] = v;
                } else {
                    bhalf o = f2bf(v);
                    int b = mm >> 11, l = mm & 2047;
                    int three = nn >> 10, rem = nn & 1023;
                    int h = rem >> 6, dh = rem & 63;
                    size_t bh = (size_t)(b * 16 + h);
                    if (three == 0)      Qb [(bh * 2048 + l) * 64 + dh] = o;
                    else if (three == 1) Kb [(bh * 2048 + l) * 64 + dh] = o;
                    else                 Vtb[(bh * 64 + dh) * 2048 + l] = o;
                }
            }
        }
    }
}

// ---------------------------------------------------------------------------
// Causal flash attention, swapped-QK^T / in-register softmax.
// grid (32, B*H), 256 threads = 4 waves; block owns 64 q-rows (wave: 16).
// Swapped MFMA: S^T tile = mfma(K_frag, Q_frag) -> each lane owns one q-row
// (q = lane&15) and 32 k-values per 128-k-tile, permuted so the PV
// A-fragment is lane-local (zero shuffles, no P LDS buffer).
// K-row permutation: row = (j>>1)*32 + (i>>2)*8 + (j&1)*4 + (i&3), i=frag row.
// Q [B,H,L,DH], K [B,H,L,DH], Vt [B,H,DH,L]; O -> [B,L,D] bf16.
// ---------------------------------------------------------------------------
__global__ __launch_bounds__(256, 4) void attn_fwd(
        const bhalf* __restrict__ Qb, const bhalf* __restrict__ Kb,
        const bhalf* __restrict__ Vtb, bhalf* __restrict__ Ob) {
    __shared__ bhalf Ks[128 * 64];    // [krow][d]  swizzle f(row)=(row&3)|(((row>>3)&1)<<2)
    __shared__ bhalf Vs[64 * 128];    // [d][kcol]  swizzle row&15

    const int qb  = 31 - blockIdx.x;   // heavy tiles dispatch first
    const int bh  = blockIdx.y;
    const int tid = threadIdx.x;
    const int w = tid >> 6, lane = tid & 63;
    const int g = lane >> 4, cl = lane & 15;

    const bhalf* Q  = Qb  + (size_t)bh * L_ * DH_;
    const bhalf* Kp = Kb  + (size_t)bh * L_ * DH_;
    const bhalf* Vt = Vtb + (size_t)bh * DH_ * L_;

    const int q0w    = qb * 64 + w * 16;   // wave's first q-row
    const int q_lane = q0w + cl;           // this lane's softmax row

    // Q fragment (B-operand): lane holds Q[q0w+cl][s*32 + g*8 .. +7]
    bf16x8 qf[2];
#pragma unroll
    for (int s = 0; s < 2; s++)
        qf[s] = *(const bf16x8*)(Q + (size_t)(q0w + cl) * 64 + s * 32 + g * 8);

    f32x4 oacc[4] = {};                    // O[q=g*4+r][d=dj*16+cl]
    float m = -__builtin_inff(), l = 0.f;

    const int nkt = (qb >> 1) + 1;
    for (int kt = 0; kt < nkt; ++kt) {
        __syncthreads();
        // stage K tile [128][64], custom f(row) (pre-swizzled source)
#pragma unroll
        for (int r = 0; r < 4; r++) {
            int c = r * 256 + tid;
            int row = c >> 3, p = c & 7;
            int f = (row & 3) | (((row >> 3) & 1) << 2);
            __builtin_amdgcn_global_load_lds(
                GPTR(Kp + (size_t)(kt * 128 + row) * 64 + (p ^ f) * 8),
                SPTR(Ks + (r * 256 + w * 64) * 8), 16, 0, 0);
        }
        // stage Vt tile [64][128], f(row)=row&15
#pragma unroll
        for (int r = 0; r < 4; r++) {
            int c = r * 256 + tid;
            int row = c >> 4, p = c & 15;
            __builtin_amdgcn_global_load_lds(
                GPTR(Vt + (size_t)row * L_ + kt * 128 + (p ^ (row & 15)) * 8),
                SPTR(Vs + (r * 256 + w * 64) * 8), 16, 0, 0);
        }
        __syncthreads();

        // S^T = K @ Q^T : p8[j][r] = S[q=cl][k = (j>>1)*32 + g*8 + (j&1)*4 + r]
        f32x4 p8[8] = {};
#pragma unroll
        for (int s = 0; s < 2; s++) {
            bf16x8 kf[8];
#pragma unroll
            for (int j = 0; j < 8; j++) {
                int row = (j >> 1) * 32 + (cl >> 2) * 8 + (j & 1) * 4 + (cl & 3);
                int f = (row & 3) | (((row >> 3) & 1) << 2);
                int ch = s * 4 + g;
                kf[j] = *(const bf16x8*)(Ks + row * 64 + ((ch ^ f) * 8));
            }
#pragma unroll
            for (int j = 0; j < 8; j++)
                p8[j] = __builtin_amdgcn_mfma_f32_16x16x32_bf16(
                    kf[j], qf[s], p8[j], 0, 0, 0);
        }

        // in-register online softmax for q = q_lane (values spread over 4 g's)
        const bool lastT = (kt == nkt - 1);
        float mx = -__builtin_inff();
#pragma unroll
        for (int j = 0; j < 8; j++) {
#pragma unroll
            for (int r = 0; r < 4; r++) {
                float v = p8[j][r] * 0.125f;
                if (lastT) {
                    int ka = kt * 128 + (j >> 1) * 32 + g * 8 + ((j & 1) << 2) + r;
                    v = (ka > q_lane) ? -__builtin_inff() : v;
                }
                p8[j][r] = v;
                mx = fmaxf(mx, v);
            }
        }
        mx = fmaxf(mx, __shfl_xor(mx, 16));
        mx = fmaxf(mx, __shfl_xor(mx, 32));
        float mnew  = fmaxf(m, mx);
        float alpha = __expf(m - mnew);    // first tile: exp(-inf)=0, oacc=0 anyway
        m = mnew;

        // rescale O accumulator (alpha for row g*4+r lives in lane g*4+r)
#pragma unroll
        for (int r = 0; r < 4; r++) {
            float ar = __shfl(alpha, g * 4 + r);
#pragma unroll
            for (int dj = 0; dj < 4; dj++) oacc[dj][r] *= ar;
        }

        // exp + row-sum
        float ls = 0.f;
#pragma unroll
        for (int j = 0; j < 8; j++)
#pragma unroll
            for (int r = 0; r < 4; r++) {
                float e = __expf(p8[j][r] - mnew);
                p8[j][r] = e;
                ls += e;
            }
        ls += __shfl_xor(ls, 16);
        ls += __shfl_xor(ls, 32);
        l = l * alpha + ls;

        // PV: A-fragment lane-local by construction
#pragma unroll
        for (int ks = 0; ks < 4; ks++) {
            bf16x8 pf;
#pragma unroll
            for (int e = 0; e < 8; e++)
                pf[e] = (__bf16)p8[2 * ks + (e >> 2)][e & 3];
            bf16x8 vf[4];
#pragma unroll
            for (int dj = 0; dj < 4; dj++) {
                int vrow = dj * 16 + cl;
                int ch = ks * 4 + g;
                vf[dj] = *(const bf16x8*)(Vs + vrow * 128 + ((ch ^ (vrow & 15)) * 8));
            }
#pragma unroll
            for (int dj = 0; dj < 4; dj++)
                oacc[dj] = __builtin_amdgcn_mfma_f32_16x16x32_bf16(
                    pf, vf[dj], oacc[dj], 0, 0, 0);
        }
    }

    // epilogue: divide by denom (+1e-6 per reference), write O [B,L,D]
    const int b = bh >> 4, h = bh & 15;
#pragma unroll
    for (int r = 0; r < 4; r++) {
        float lr  = __shfl(l, g * 4 + r);
        float inv = 1.f / (lr + 1e-6f);
        int qrow = q0w + g * 4 + r;
#pragma unroll
        for (int dj = 0; dj < 4; dj++)
            Ob[((size_t)b * L_ + qrow) * D_ + h * 64 + dj * 16 + cl] =
                f2bf(oacc[dj][r] * inv);
    }
}

// ---------------------------------------------------------------------------
extern "C" void kernel_launch(void* const* d_in, const int* in_sizes, int n_in,
                              void* d_out, int out_size, void* d_ws, size_t ws_size,
                              hipStream_t stream) {
    const void* x     = d_in[0];   // [B,L,D]     f32 or bf16
    const void* Wqkv  = d_in[1];   // [D, 3D]
    const void* bqkv  = d_in[2];   // [3D]
    const void* Wproj = d_in[3];   // [D, D]
    const void* bproj = d_in[4];   // [D]

    char* ws = (char*)d_ws;
    const size_t SZ_FLG = 256;
    const size_t SZ_WQT = (size_t)3 * D_ * D_ * 2;        //  6 MB  Wqkv^T [3D][D]
    const size_t SZ_WPT = (size_t)D_ * D_ * 2;            //  2 MB  Wproj^T [D][D]
    const size_t SZ_X   = (size_t)B_ * L_ * D_ * 2;       //  8 MB  x bf16
    const size_t SZ_BUF = (size_t)B_ * H_ * L_ * DH_ * 2; //  8 MB  each

    int*   flag = (int*)ws;
    bhalf* Wq_t = (bhalf*)(ws + SZ_FLG);
    bhalf* Wp_t = (bhalf*)(ws + SZ_FLG + SZ_WQT);
    bhalf* Xb   = (bhalf*)(ws + SZ_FLG + SZ_WQT + SZ_WPT);
    bhalf* Qbuf = (bhalf*)(ws + SZ_FLG + SZ_WQT + SZ_WPT + SZ_X);
    bhalf* Kbuf = (bhalf*)(ws + SZ_FLG + SZ_WQT + SZ_WPT + SZ_X + SZ_BUF);
    bhalf* Vtbf = (bhalf*)(ws + SZ_FLG + SZ_WQT + SZ_WPT + SZ_X + 2 * SZ_BUF);
    bhalf* Obuf = (bhalf*)(ws + SZ_FLG + SZ_WQT + SZ_WPT + SZ_X + 3 * SZ_BUF);

    const int M = B_ * L_;   // 4096

    // 0. runtime dtype detection from x's bit patterns
    detect_dtype<<<1, 64, 0, stream>>>((const uint32*)x, flag);

    // 1. canonicalize inputs to bf16 workspace
    conv_bf16<<<2048, 256, 0, stream>>>(x, Xb, (B_ * L_ * D_) / 4, flag);
    tr_conv<<<dim3(3 * D_ / 32, D_ / 32), dim3(32, 8), 0, stream>>>(
        Wqkv, Wq_t, D_, 3 * D_, flag);
    tr_conv<<<dim3(D_ / 32, D_ / 32), dim3(32, 8), 0, stream>>>(
        Wproj, Wp_t, D_, D_, flag);

    // 2. QKV projection + scatter to Q,K [B,H,L,DH] and Vt [B,H,DH,L]
    gemm_bt<1><<<dim3(3 * D_ / 128, M / 128), 256, 0, stream>>>(
        Xb, Wq_t, bqkv, nullptr, Qbuf, Kbuf, Vtbf, M, 3 * D_, D_, flag);

    // 3. causal flash attention -> Obuf [B,L,D] bf16
    attn_fwd<<<dim3(32, B_ * H_), 256, 0, stream>>>(Qbuf, Kbuf, Vtbf, Obuf);

    // 4. output projection -> d_out (f32 or bf16 per flag)
    gemm_bt<0><<<dim3(D_ / 128, M / 128), 256, 0, stream>>>(
        Obuf, Wp_t, bproj, d_out, nullptr, nullptr, nullptr, M, D_, D_, flag);
}

// Round 4
// 140.596 us; speedup vs baseline: 1.7400x; 1.1297x over previous
//
#include <hip/hip_runtime.h>

// ---------------------------------------------------------------------------
// Fused causal MHA:  out = attn(x@Wqkv+b) @ Wproj + bproj
// B=2, L=2048, D=1024, H=16, DH=64
// Device buffers may be f32 or bf16 -- detected at runtime from x's bit
// patterns; all compute is bf16 MFMA internally.
// ---------------------------------------------------------------------------

typedef __bf16 bf16x8 __attribute__((ext_vector_type(8)));
typedef float  f32x4  __attribute__((ext_vector_type(4)));
typedef unsigned short bhalf;
typedef unsigned int   uint32;

#define B_  2
#define L_  2048
#define D_  1024
#define H_  16
#define DH_ 64

#define GPTR(p) ((const __attribute__((address_space(1))) void*)(p))
#define SPTR(p) ((__attribute__((address_space(3))) void*)(p))

static __device__ __forceinline__ float bf2f(bhalf u) {
    union { uint32 u; float f; } x; x.u = ((uint32)u) << 16; return x.f;
}
static __device__ __forceinline__ bhalf f2bf(float f) {
    union { float f; uint32 u; } x; x.f = f;
    uint32 r = x.u + 0x7FFFu + ((x.u >> 16) & 1u);   // RNE
    return (bhalf)(r >> 16);
}

// ---------------------------------------------------------------------------
// dtype detection: x ~ N(0,1). If words are f32, their low 16 bits viewed as
// bf16 have ~uniform-random exponents (garbage); if genuine bf16, exponents
// cluster near 0x7F. flag: 0 = f32 buffers, 1 = bf16 buffers.
// ---------------------------------------------------------------------------
__global__ void detect_dtype(const uint32* __restrict__ xw, int* __restrict__ flag) {
    int t = threadIdx.x;                     // 64 threads
    uint32 w = xw[t];
    uint32 e = (w >> 7) & 0xFFu;             // exponent of low-half bf16
    int g = (e < 0x6Fu || e > 0x84u) ? 1 : 0;  // |v|<2^-16 or |v|>32 => garbage
#pragma unroll
    for (int off = 32; off; off >>= 1) g += __shfl_xor(g, off);
    if (t == 0) *flag = (g > 16) ? 0 : 1;
}

// ---------------------------------------------------------------------------
// convert x (f32 or bf16) -> bf16, 4 elems/thread
// ---------------------------------------------------------------------------
__global__ void conv_bf16(const void* __restrict__ in, bhalf* __restrict__ out,
                          int n4, const int* __restrict__ flag) {
    const bool isb = (*flag != 0);
    for (int i = blockIdx.x * blockDim.x + threadIdx.x; i < n4;
         i += gridDim.x * blockDim.x) {
        if (isb) {
            ((uint2*)out)[i] = ((const uint2*)in)[i];
        } else {
            float4 v = ((const float4*)in)[i];
            uint2 o;
            o.x = (uint32)f2bf(v.x) | ((uint32)f2bf(v.y) << 16);
            o.y = (uint32)f2bf(v.z) | ((uint32)f2bf(v.w) << 16);
            ((uint2*)out)[i] = o;
        }
    }
}

// ---------------------------------------------------------------------------
// transpose + convert: in [R][C] (f32 or bf16) -> out [C][R] bf16
// ---------------------------------------------------------------------------
__global__ void tr_conv(const void* __restrict__ in, bhalf* __restrict__ out,
                        int R, int C, const int* __restrict__ flag) {
    __shared__ bhalf t[32][33];
    const bool isb = (*flag != 0);
    int bx = blockIdx.x, by = blockIdx.y;
    int tx = threadIdx.x, ty = threadIdx.y;   // (32, 8)
#pragma unroll
    for (int i = 0; i < 32; i += 8) {
        size_t idx = (size_t)(by * 32 + ty + i) * C + bx * 32 + tx;
        t[ty + i][tx] = isb ? ((const bhalf*)in)[idx]
                            : f2bf(((const float*)in)[idx]);
    }
    __syncthreads();
#pragma unroll
    for (int i = 0; i < 32; i += 8)
        out[(size_t)(bx * 32 + ty + i) * R + by * 32 + tx] = t[tx][ty + i];
}

// ---------------------------------------------------------------------------
// GEMM  C[M][N] = A[M][K] @ Bt[N][K]^T + bias[N]     (A, Bt are bf16)
// 128x128 tile, BK=32, 256 threads = 4 waves each 64x64.
// MODE 0: write C row-major (f32 or bf16 per flag) to C0.
// MODE 1: QKV scatter: Q,K -> [B,H,L,DH] bf16, V -> Vt [B,H,DH,L] bf16.
// ---------------------------------------------------------------------------
template <int MODE>
__global__ __launch_bounds__(256) void gemm_bt(
        const bhalf* __restrict__ A, const bhalf* __restrict__ Bt,
        const void* __restrict__ bias,
        void* __restrict__ C0, bhalf* __restrict__ Qb,
        bhalf* __restrict__ Kb, bhalf* __restrict__ Vtb,
        int M, int N, int K, const int* __restrict__ flag) {
    __shared__ bhalf As[128 * 32];
    __shared__ bhalf Bs[128 * 32];
    const bool isb = (*flag != 0);
    const int tid  = threadIdx.x;
    const int w    = tid >> 6, lane = tid & 63;
    const int g    = lane >> 4, cl = lane & 15;
    const int m0   = blockIdx.y * 128, n0 = blockIdx.x * 128;
    const int wr   = (w >> 1) * 64, wc = (w & 1) * 64;

    f32x4 acc[4][4] = {};

    const bhalf* a0 = A  + (size_t)m0 * K;
    const bhalf* b0 = Bt + (size_t)n0 * K;

    for (int kk = 0; kk < K; kk += 32) {
        __syncthreads();
        // stage A,B tiles (chunk-XOR-swizzled source, linear LDS dest)
#pragma unroll
        for (int r = 0; r < 2; r++) {
            int c = r * 256 + tid;
            int row = c >> 2, p = c & 3;
            int gch = p ^ (row & 3);
            __builtin_amdgcn_global_load_lds(
                GPTR(a0 + (size_t)row * K + kk + gch * 8),
                SPTR(As + (r * 256 + w * 64) * 8), 16, 0, 0);
            __builtin_amdgcn_global_load_lds(
                GPTR(b0 + (size_t)row * K + kk + gch * 8),
                SPTR(Bs + (r * 256 + w * 64) * 8), 16, 0, 0);
        }
        __syncthreads();

        bf16x8 af[4], bf[4];
#pragma unroll
        for (int i = 0; i < 4; i++) {
            int ra = wr + i * 16 + cl;
            af[i] = *(const bf16x8*)(As + ra * 32 + ((g ^ (ra & 3)) * 8));
            int rb = wc + i * 16 + cl;
            bf[i] = *(const bf16x8*)(Bs + rb * 32 + ((g ^ (rb & 3)) * 8));
        }
#pragma unroll
        for (int i = 0; i < 4; i++)
#pragma unroll
            for (int j = 0; j < 4; j++)
                acc[i][j] = __builtin_amdgcn_mfma_f32_16x16x32_bf16(
                    af[i], bf[j], acc[i][j], 0, 0, 0);
    }

    // epilogue: C/D layout col = lane&15, row = (lane>>4)*4 + reg
#pragma unroll
    for (int i = 0; i < 4; i++) {
#pragma unroll
        for (int j = 0; j < 4; j++) {
            int nn = n0 + wc + j * 16 + cl;
            float bv = isb ? bf2f(((const bhalf*)bias)[nn])
                           : ((const float*)bias)[nn];
#pragma unroll
            for (int r = 0; r < 4; r++) {
                int mm = m0 + wr + i * 16 + g * 4 + r;
                float v = acc[i][j][r] + bv;
                if (MODE == 0) {
                    if (isb) ((bhalf*)C0)[(size_t)mm * N + nn] = f2bf(v);
                    else     ((float*)C0)[(size_t)mm * N + nn] = v;
                } else {
                    bhalf o = f2bf(v);
                    int b = mm >> 11, l = mm & 2047;
                    int three = nn >> 10, rem = nn & 1023;
                    int h = rem >> 6, dh = rem & 63;
                    size_t bh = (size_t)(b * 16 + h);
                    if (three == 0)      Qb [(bh * 2048 + l) * 64 + dh] = o;
                    else if (three == 1) Kb [(bh * 2048 + l) * 64 + dh] = o;
                    else                 Vtb[(bh * 64 + dh) * 2048 + l] = o;
                }
            }
        }
    }
}

// ---------------------------------------------------------------------------
// Causal flash attention, swapped-QK^T / in-register softmax.
// 512 blocks x 256 threads (4 waves). Each block handles TWO 64-row q-tiles
// (qbA = heavy, qbB = light; nktA+nktB = 17 for every block -> perfect
// balance). K/V tiles double-buffered in LDS with prefetch (one barrier per
// tile). XCD-aware block swizzle groups same-(b,h) blocks on one XCD's L2.
// Q [B,H,L,DH], K [B,H,L,DH], Vt [B,H,DH,L]; O -> [B,L,D] bf16.
// ---------------------------------------------------------------------------

// stage K/V tile kt into LDS buffer BUF (pre-swizzled global source)
#define STAGE(BUF, KT) do {                                                   \
    int ktv = (KT);                                                           \
    _Pragma("unroll")                                                         \
    for (int r = 0; r < 4; r++) {                                             \
        int c = r * 256 + tid;                                                \
        int row = c >> 3, p = c & 7;                                          \
        int fsw = (row & 3) | (((row >> 3) & 1) << 2);                        \
        __builtin_amdgcn_global_load_lds(                                     \
            GPTR(Kp + (size_t)(ktv * 128 + row) * 64 + (p ^ fsw) * 8),        \
            SPTR(Ks[BUF] + (r * 256 + w * 64) * 8), 16, 0, 0);                \
    }                                                                         \
    _Pragma("unroll")                                                         \
    for (int r = 0; r < 4; r++) {                                             \
        int c = r * 256 + tid;                                                \
        int row = c >> 4, p = c & 15;                                         \
        __builtin_amdgcn_global_load_lds(                                     \
            GPTR(Vt + (size_t)row * L_ + ktv * 128 + (p ^ (row & 15)) * 8),   \
            SPTR(Vs[BUF] + (r * 256 + w * 64) * 8), 16, 0, 0);                \
    }                                                                         \
} while (0)

// one k-tile: S^T = K@Q^T -> in-register online softmax -> O += P@Vt^T
#define ATTN_TILE(BUF, KT, QF, QLANE, MVAR, LVAR, OACC, MASK) do {            \
    f32x4 p8[8] = {};                                                         \
    _Pragma("unroll")                                                         \
    for (int s = 0; s < 2; s++) {                                             \
        bf16x8 kf[8];                                                         \
        _Pragma("unroll")                                                     \
        for (int j = 0; j < 8; j++) {                                         \
            int row = (j >> 1) * 32 + (cl >> 2) * 8 + (j & 1) * 4 + (cl & 3); \
            int fsw = (row & 3) | (((row >> 3) & 1) << 2);                    \
            int ch = s * 4 + g;                                               \
            kf[j] = *(const bf16x8*)(Ks[BUF] + row * 64 + ((ch ^ fsw) * 8));  \
        }                                                                     \
        __builtin_amdgcn_s_setprio(1);                                        \
        _Pragma("unroll")                                                     \
        for (int j = 0; j < 8; j++)                                           \
            p8[j] = __builtin_amdgcn_mfma_f32_16x16x32_bf16(                  \
                kf[j], QF[s], p8[j], 0, 0, 0);                                \
        __builtin_amdgcn_s_setprio(0);                                        \
    }                                                                         \
    float mx = -__builtin_inff();                                             \
    _Pragma("unroll")                                                         \
    for (int j = 0; j < 8; j++) {                                             \
        _Pragma("unroll")                                                     \
        for (int r = 0; r < 4; r++) {                                         \
            float v = p8[j][r] * 0.125f;                                      \
            if (MASK) {                                                       \
                int ka = (KT) * 128 + (j >> 1) * 32 + g * 8 + ((j & 1) << 2) + r; \
                v = (ka > (QLANE)) ? -__builtin_inff() : v;                   \
            }                                                                 \
            p8[j][r] = v;                                                     \
            mx = fmaxf(mx, v);                                                \
        }                                                                     \
    }                                                                         \
    mx = fmaxf(mx, __shfl_xor(mx, 16));                                       \
    mx = fmaxf(mx, __shfl_xor(mx, 32));                                       \
    float mnew = fmaxf(MVAR, mx);                                             \
    float alpha = __expf(MVAR - mnew);                                        \
    MVAR = mnew;                                                              \
    _Pragma("unroll")                                                         \
    for (int r = 0; r < 4; r++) {                                             \
        float ar = __shfl(alpha, g * 4 + r);                                  \
        _Pragma("unroll")                                                     \
        for (int dj = 0; dj < 4; dj++) OACC[dj][r] *= ar;                     \
    }                                                                         \
    float ls = 0.f;                                                           \
    _Pragma("unroll")                                                         \
    for (int j = 0; j < 8; j++)                                               \
        _Pragma("unroll")                                                     \
        for (int r = 0; r < 4; r++) {                                         \
            float e = __expf(p8[j][r] - mnew);                                \
            p8[j][r] = e;                                                     \
            ls += e;                                                          \
        }                                                                     \
    ls += __shfl_xor(ls, 16);                                                 \
    ls += __shfl_xor(ls, 32);                                                 \
    LVAR = LVAR * alpha + ls;                                                 \
    _Pragma("unroll")                                                         \
    for (int ks = 0; ks < 4; ks++) {                                          \
        bf16x8 pf;                                                            \
        _Pragma("unroll")                                                     \
        for (int e = 0; e < 8; e++)                                           \
            pf[e] = (__bf16)p8[2 * ks + (e >> 2)][e & 3];                     \
        bf16x8 vf[4];                                                         \
        _Pragma("unroll")                                                     \
        for (int dj = 0; dj < 4; dj++) {                                      \
            int vrow = dj * 16 + cl;                                          \
            int ch = ks * 4 + g;                                              \
            vf[dj] = *(const bf16x8*)(Vs[BUF] + vrow * 128 + ((ch ^ (vrow & 15)) * 8)); \
        }                                                                     \
        __builtin_amdgcn_s_setprio(1);                                        \
        _Pragma("unroll")                                                     \
        for (int dj = 0; dj < 4; dj++)                                        \
            OACC[dj] = __builtin_amdgcn_mfma_f32_16x16x32_bf16(               \
                pf, vf[dj], OACC[dj], 0, 0, 0);                               \
        __builtin_amdgcn_s_setprio(0);                                        \
    }                                                                         \
} while (0)

__global__ __launch_bounds__(256, 2) void attn_fwd(
        const bhalf* __restrict__ Qb, const bhalf* __restrict__ Kb,
        const bhalf* __restrict__ Vtb, bhalf* __restrict__ Ob) {
    __shared__ bhalf Ks[2][128 * 64];   // [buf][krow][d]  swz f(row)=(row&3)|(((row>>3)&1)<<2)
    __shared__ bhalf Vs[2][64 * 128];   // [buf][d][kcol]  swz row&15

    // XCD-aware swizzle: same-(b,h) blocks land on one XCD (bid%8 = XCD)
    const int bid  = blockIdx.x;              // 0..511
    const int xcd  = bid & 7, slot = bid >> 3;
    const int bx   = slot & 15;               // 0..15
    const int bh   = xcd + 8 * (slot >> 4);   // 0..31
    const int qbA  = 31 - bx;                 // heavy half (nktA = 9..16)
    const int qbB  = bx;                      // light half (nktB = 1..8)

    const int tid = threadIdx.x;
    const int w = tid >> 6, lane = tid & 63;
    const int g = lane >> 4, cl = lane & 15;

    const bhalf* Q  = Qb  + (size_t)bh * L_ * DH_;
    const bhalf* Kp = Kb  + (size_t)bh * L_ * DH_;
    const bhalf* Vt = Vtb + (size_t)bh * DH_ * L_;

    const int q0A = qbA * 64 + w * 16, qlA = q0A + cl;
    const int q0B = qbB * 64 + w * 16, qlB = q0B + cl;

    // Q fragments (B-operand) for both halves, in registers for whole block
    bf16x8 qfA[2], qfB[2];
#pragma unroll
    for (int s = 0; s < 2; s++) {
        qfA[s] = *(const bf16x8*)(Q + (size_t)(q0A + cl) * 64 + s * 32 + g * 8);
        qfB[s] = *(const bf16x8*)(Q + (size_t)(q0B + cl) * 64 + s * 32 + g * 8);
    }

    f32x4 oA[4] = {}, oB[4] = {};
    float mA = -__builtin_inff(), lA = 0.f;
    float mB = -__builtin_inff(), lB = 0.f;

    const int nktA = (qbA >> 1) + 1;
    const int nktB = (qbB >> 1) + 1;
    const int ntot = nktA + nktB;             // == 17 for all blocks

    STAGE(0, 0);
    __syncthreads();

    for (int t = 0; t < ntot; ++t) {
        int cur = t & 1;
        if (t + 1 < ntot) {                   // prefetch next tile
            int tn = t + 1;
            int ktn = (tn < nktA) ? tn : (tn - nktA);
            STAGE(cur ^ 1, ktn);
        }
        if (t < nktA) {
            ATTN_TILE(cur, t, qfA, qlA, mA, lA, oA, (t == nktA - 1));
        } else {
            int kt = t - nktA;
            ATTN_TILE(cur, kt, qfB, qlB, mB, lB, oB, (kt == nktB - 1));
        }
        __syncthreads();   // next buffer staged; current free to overwrite
    }

    // epilogue: divide by denom (+1e-6 per reference), write O [B,L,D]
    const int b = bh >> 4, h = bh & 15;
#pragma unroll
    for (int r = 0; r < 4; r++) {
        float lrA = __shfl(lA, g * 4 + r);
        float lrB = __shfl(lB, g * 4 + r);
        float invA = 1.f / (lrA + 1e-6f);
        float invB = 1.f / (lrB + 1e-6f);
        int qrA = q0A + g * 4 + r, qrB = q0B + g * 4 + r;
#pragma unroll
        for (int dj = 0; dj < 4; dj++) {
            Ob[((size_t)b * L_ + qrA) * D_ + h * 64 + dj * 16 + cl] =
                f2bf(oA[dj][r] * invA);
            Ob[((size_t)b * L_ + qrB) * D_ + h * 64 + dj * 16 + cl] =
                f2bf(oB[dj][r] * invB);
        }
    }
}

// ---------------------------------------------------------------------------
extern "C" void kernel_launch(void* const* d_in, const int* in_sizes, int n_in,
                              void* d_out, int out_size, void* d_ws, size_t ws_size,
                              hipStream_t stream) {
    const void* x     = d_in[0];   // [B,L,D]     f32 or bf16
    const void* Wqkv  = d_in[1];   // [D, 3D]
    const void* bqkv  = d_in[2];   // [3D]
    const void* Wproj = d_in[3];   // [D, D]
    const void* bproj = d_in[4];   // [D]

    char* ws = (char*)d_ws;
    const size_t SZ_FLG = 256;
    const size_t SZ_WQT = (size_t)3 * D_ * D_ * 2;        //  6 MB  Wqkv^T [3D][D]
    const size_t SZ_WPT = (size_t)D_ * D_ * 2;            //  2 MB  Wproj^T [D][D]
    const size_t SZ_X   = (size_t)B_ * L_ * D_ * 2;       //  8 MB  x bf16
    const size_t SZ_BUF = (size_t)B_ * H_ * L_ * DH_ * 2; //  8 MB  each

    int*   flag = (int*)ws;
    bhalf* Wq_t = (bhalf*)(ws + SZ_FLG);
    bhalf* Wp_t = (bhalf*)(ws + SZ_FLG + SZ_WQT);
    bhalf* Xb   = (bhalf*)(ws + SZ_FLG + SZ_WQT + SZ_WPT);
    bhalf* Qbuf = (bhalf*)(ws + SZ_FLG + SZ_WQT + SZ_WPT + SZ_X);
    bhalf* Kbuf = (bhalf*)(ws + SZ_FLG + SZ_WQT + SZ_WPT + SZ_X + SZ_BUF);
    bhalf* Vtbf = (bhalf*)(ws + SZ_FLG + SZ_WQT + SZ_WPT + SZ_X + 2 * SZ_BUF);
    bhalf* Obuf = (bhalf*)(ws + SZ_FLG + SZ_WQT + SZ_WPT + SZ_X + 3 * SZ_BUF);

    const int M = B_ * L_;   // 4096

    // 0. runtime dtype detection from x's bit patterns
    detect_dtype<<<1, 64, 0, stream>>>((const uint32*)x, flag);

    // 1. canonicalize inputs to bf16 workspace
    conv_bf16<<<2048, 256, 0, stream>>>(x, Xb, (B_ * L_ * D_) / 4, flag);
    tr_conv<<<dim3(3 * D_ / 32, D_ / 32), dim3(32, 8), 0, stream>>>(
        Wqkv, Wq_t, D_, 3 * D_, flag);
    tr_conv<<<dim3(D_ / 32, D_ / 32), dim3(32, 8), 0, stream>>>(
        Wproj, Wp_t, D_, D_, flag);

    // 2. QKV projection + scatter to Q,K [B,H,L,DH] and Vt [B,H,DH,L]
    gemm_bt<1><<<dim3(3 * D_ / 128, M / 128), 256, 0, stream>>>(
        Xb, Wq_t, bqkv, nullptr, Qbuf, Kbuf, Vtbf, M, 3 * D_, D_, flag);

    // 3. causal flash attention -> Obuf [B,L,D] bf16
    attn_fwd<<<dim3(512), 256, 0, stream>>>(Qbuf, Kbuf, Vtbf, Obuf);

    // 4. output projection -> d_out (f32 or bf16 per flag)
    gemm_bt<0><<<dim3(D_ / 128, M / 128), 256, 0, stream>>>(
        Obuf, Wp_t, bproj, d_out, nullptr, nullptr, nullptr, M, D_, D_, flag);
}

// Round 5
// 134.099 us; speedup vs baseline: 1.8243x; 1.0484x over previous
//
#include <hip/hip_runtime.h>

// ---------------------------------------------------------------------------
// Fused causal MHA:  out = attn(x@Wqkv+b) @ Wproj + bproj
// B=2, L=2048, D=1024, H=16, DH=64
// Device buffers may be f32 or bf16 -- detected at runtime from x's bit
// patterns; all compute is bf16 MFMA internally.
// ---------------------------------------------------------------------------

typedef __bf16 bf16x8 __attribute__((ext_vector_type(8)));
typedef float  f32x4  __attribute__((ext_vector_type(4)));
typedef unsigned short bhalf;
typedef unsigned int   uint32;

#define B_  2
#define L_  2048
#define D_  1024
#define H_  16
#define DH_ 64

#define GPTR(p) ((const __attribute__((address_space(1))) void*)(p))
#define SPTR(p) ((__attribute__((address_space(3))) void*)(p))

static __device__ __forceinline__ float bf2f(bhalf u) {
    union { uint32 u; float f; } x; x.u = ((uint32)u) << 16; return x.f;
}
static __device__ __forceinline__ bhalf f2bf(float f) {
    union { float f; uint32 u; } x; x.f = f;
    uint32 r = x.u + 0x7FFFu + ((x.u >> 16) & 1u);   // RNE
    return (bhalf)(r >> 16);
}

// ---------------------------------------------------------------------------
// dtype detection: x ~ N(0,1). If words are f32, their low 16 bits viewed as
// bf16 have ~uniform-random exponents (garbage); if genuine bf16, exponents
// cluster near 0x7F. flag: 0 = f32 buffers, 1 = bf16 buffers.
// ---------------------------------------------------------------------------
__global__ void detect_dtype(const uint32* __restrict__ xw, int* __restrict__ flag) {
    int t = threadIdx.x;                     // 64 threads
    uint32 w = xw[t];
    uint32 e = (w >> 7) & 0xFFu;             // exponent of low-half bf16
    int g = (e < 0x6Fu || e > 0x84u) ? 1 : 0;  // |v|<2^-16 or |v|>32 => garbage
#pragma unroll
    for (int off = 32; off; off >>= 1) g += __shfl_xor(g, off);
    if (t == 0) *flag = (g > 16) ? 0 : 1;
}

// ---------------------------------------------------------------------------
// convert x (f32 or bf16) -> bf16, 4 elems/thread
// ---------------------------------------------------------------------------
__global__ void conv_bf16(const void* __restrict__ in, bhalf* __restrict__ out,
                          int n4, const int* __restrict__ flag) {
    const bool isb = (*flag != 0);
    for (int i = blockIdx.x * blockDim.x + threadIdx.x; i < n4;
         i += gridDim.x * blockDim.x) {
        if (isb) {
            ((uint2*)out)[i] = ((const uint2*)in)[i];
        } else {
            float4 v = ((const float4*)in)[i];
            uint2 o;
            o.x = (uint32)f2bf(v.x) | ((uint32)f2bf(v.y) << 16);
            o.y = (uint32)f2bf(v.z) | ((uint32)f2bf(v.w) << 16);
            ((uint2*)out)[i] = o;
        }
    }
}

// ---------------------------------------------------------------------------
// transpose + convert: in [R][C] (f32 or bf16) -> out [C][R] bf16
// ---------------------------------------------------------------------------
__global__ void tr_conv(const void* __restrict__ in, bhalf* __restrict__ out,
                        int R, int C, const int* __restrict__ flag) {
    __shared__ bhalf t[32][33];
    const bool isb = (*flag != 0);
    int bx = blockIdx.x, by = blockIdx.y;
    int tx = threadIdx.x, ty = threadIdx.y;   // (32, 8)
#pragma unroll
    for (int i = 0; i < 32; i += 8) {
        size_t idx = (size_t)(by * 32 + ty + i) * C + bx * 32 + tx;
        t[ty + i][tx] = isb ? ((const bhalf*)in)[idx]
                            : f2bf(((const float*)in)[idx]);
    }
    __syncthreads();
#pragma unroll
    for (int i = 0; i < 32; i += 8)
        out[(size_t)(bx * 32 + ty + i) * R + by * 32 + tx] = t[tx][ty + i];
}

// ---------------------------------------------------------------------------
// GEMM  C[M][N] = A[M][K] @ Bt[N][K]^T + bias[N]     (A, Bt are bf16)
// 128x128 tile, BK=32, 256 threads = 4 waves each 64x64.
// Double-buffered LDS, prefetch-next-before-compute (T3-minimal 2-phase):
// one __syncthreads per k-step; the vmcnt drain lands AFTER the MFMA work,
// so load latency hides under compute.
// Chunk permutation pos = (c + row + (row>>2)) & 3 gives 2-way (free) bank
// access on ds_read_b128 (old XOR-(row&3) form was 4-way).
// MODE 0: write C row-major (f32 or bf16 per flag) to C0.
// MODE 1: QKV scatter: Q,K -> [B,H,L,DH] bf16, V -> Vt [B,H,DH,L] bf16.
// ---------------------------------------------------------------------------

// stage 128x32 A- and B-tiles at k-offset KK into LDS buffer BUF.
// linear LDS dest (wave-uniform base + lane*16B); source chunk pre-permuted:
// stored position p holds logical chunk (p - row - (row>>2)) & 3.
#define GSTAGE(BUF, KK) do {                                                  \
    int kko = (KK);                                                           \
    _Pragma("unroll")                                                         \
    for (int r = 0; r < 2; r++) {                                             \
        int c = r * 256 + tid;                                                \
        int row = c >> 2, p = c & 3;                                          \
        int gch = (p - row - (row >> 2)) & 3;                                 \
        __builtin_amdgcn_global_load_lds(                                     \
            GPTR(a0 + (size_t)row * K + kko + gch * 8),                       \
            SPTR(As[BUF] + (r * 256 + w * 64) * 8), 16, 0, 0);                \
        __builtin_amdgcn_global_load_lds(                                     \
            GPTR(b0 + (size_t)row * K + kko + gch * 8),                       \
            SPTR(Bs[BUF] + (r * 256 + w * 64) * 8), 16, 0, 0);                \
    }                                                                         \
} while (0)

template <int MODE>
__global__ __launch_bounds__(256) void gemm_bt(
        const bhalf* __restrict__ A, const bhalf* __restrict__ Bt,
        const void* __restrict__ bias,
        void* __restrict__ C0, bhalf* __restrict__ Qb,
        bhalf* __restrict__ Kb, bhalf* __restrict__ Vtb,
        int M, int N, int K, const int* __restrict__ flag) {
    __shared__ bhalf As[2][128 * 32];
    __shared__ bhalf Bs[2][128 * 32];
    const bool isb = (*flag != 0);
    const int tid  = threadIdx.x;
    const int w    = tid >> 6, lane = tid & 63;
    const int g    = lane >> 4, cl = lane & 15;
    const int m0   = blockIdx.y * 128, n0 = blockIdx.x * 128;
    const int wr   = (w >> 1) * 64, wc = (w & 1) * 64;

    f32x4 acc[4][4] = {};

    const bhalf* a0 = A  + (size_t)m0 * K;
    const bhalf* b0 = Bt + (size_t)n0 * K;

    GSTAGE(0, 0);
    __syncthreads();

    const int nk = K >> 5;
    for (int t = 0; t < nk; ++t) {
        int cur = t & 1;
        if (t + 1 < nk) GSTAGE(cur ^ 1, (t + 1) << 5);   // prefetch next tile

        bf16x8 af[4], bf4[4];
#pragma unroll
        for (int i = 0; i < 4; i++) {
            int ra = wr + i * 16 + cl;
            af[i]  = *(const bf16x8*)(As[cur] + ra * 32 +
                                      (((g + ra + (ra >> 2)) & 3) * 8));
            int rb = wc + i * 16 + cl;
            bf4[i] = *(const bf16x8*)(Bs[cur] + rb * 32 +
                                      (((g + rb + (rb >> 2)) & 3) * 8));
        }
        __builtin_amdgcn_s_setprio(1);
#pragma unroll
        for (int i = 0; i < 4; i++)
#pragma unroll
            for (int j = 0; j < 4; j++)
                acc[i][j] = __builtin_amdgcn_mfma_f32_16x16x32_bf16(
                    af[i], bf4[j], acc[i][j], 0, 0, 0);
        __builtin_amdgcn_s_setprio(0);

        __syncthreads();   // next buffer staged; cur free to overwrite
    }

    // epilogue: C/D layout col = lane&15, row = (lane>>4)*4 + reg
#pragma unroll
    for (int i = 0; i < 4; i++) {
#pragma unroll
        for (int j = 0; j < 4; j++) {
            int nn = n0 + wc + j * 16 + cl;
            float bv = isb ? bf2f(((const bhalf*)bias)[nn])
                           : ((const float*)bias)[nn];
#pragma unroll
            for (int r = 0; r < 4; r++) {
                int mm = m0 + wr + i * 16 + g * 4 + r;
                float v = acc[i][j][r] + bv;
                if (MODE == 0) {
                    if (isb) ((bhalf*)C0)[(size_t)mm * N + nn] = f2bf(v);
                    else     ((float*)C0)[(size_t)mm * N + nn] = v;
                } else {
                    bhalf o = f2bf(v);
                    int b = mm >> 11, l = mm & 2047;
                    int three = nn >> 10, rem = nn & 1023;
                    int h = rem >> 6, dh = rem & 63;
                    size_t bh = (size_t)(b * 16 + h);
                    if (three == 0)      Qb [(bh * 2048 + l) * 64 + dh] = o;
                    else if (three == 1) Kb [(bh * 2048 + l) * 64 + dh] = o;
                    else                 Vtb[(bh * 64 + dh) * 2048 + l] = o;
                }
            }
        }
    }
}

// ---------------------------------------------------------------------------
// Causal flash attention, swapped-QK^T / in-register softmax.
// 512 blocks x 256 threads (4 waves). Each block handles TWO 64-row q-tiles
// (qbA = heavy, qbB = light; nktA+nktB = 17 for every block -> perfect
// balance). K/V tiles double-buffered in LDS with prefetch (one barrier per
// tile). XCD-aware block swizzle groups same-(b,h) blocks on one XCD's L2.
// Q [B,H,L,DH], K [B,H,L,DH], Vt [B,H,DH,L]; O -> [B,L,D] bf16.
// ---------------------------------------------------------------------------

// stage K/V tile kt into LDS buffer BUF (pre-swizzled global source)
#define STAGE(BUF, KT) do {                                                   \
    int ktv = (KT);                                                           \
    _Pragma("unroll")                                                         \
    for (int r = 0; r < 4; r++) {                                             \
        int c = r * 256 + tid;                                                \
        int row = c >> 3, p = c & 7;                                          \
        int fsw = (row & 3) | (((row >> 3) & 1) << 2);                        \
        __builtin_amdgcn_global_load_lds(                                     \
            GPTR(Kp + (size_t)(ktv * 128 + row) * 64 + (p ^ fsw) * 8),        \
            SPTR(Ks[BUF] + (r * 256 + w * 64) * 8), 16, 0, 0);                \
    }                                                                         \
    _Pragma("unroll")                                                         \
    for (int r = 0; r < 4; r++) {                                             \
        int c = r * 256 + tid;                                                \
        int row = c >> 4, p = c & 15;                                         \
        __builtin_amdgcn_global_load_lds(                                     \
            GPTR(Vt + (size_t)row * L_ + ktv * 128 + (p ^ (row & 15)) * 8),   \
            SPTR(Vs[BUF] + (r * 256 + w * 64) * 8), 16, 0, 0);                \
    }                                                                         \
} while (0)

// one k-tile: S^T = K@Q^T -> in-register online softmax -> O += P@Vt^T
#define ATTN_TILE(BUF, KT, QF, QLANE, MVAR, LVAR, OACC, MASK) do {            \
    f32x4 p8[8] = {};                                                         \
    _Pragma("unroll")                                                         \
    for (int s = 0; s < 2; s++) {                                             \
        bf16x8 kf[8];                                                         \
        _Pragma("unroll")                                                     \
        for (int j = 0; j < 8; j++) {                                         \
            int row = (j >> 1) * 32 + (cl >> 2) * 8 + (j & 1) * 4 + (cl & 3); \
            int fsw = (row & 3) | (((row >> 3) & 1) << 2);                    \
            int ch = s * 4 + g;                                               \
            kf[j] = *(const bf16x8*)(Ks[BUF] + row * 64 + ((ch ^ fsw) * 8));  \
        }                                                                     \
        __builtin_amdgcn_s_setprio(1);                                        \
        _Pragma("unroll")                                                     \
        for (int j = 0; j < 8; j++)                                           \
            p8[j] = __builtin_amdgcn_mfma_f32_16x16x32_bf16(                  \
                kf[j], QF[s], p8[j], 0, 0, 0);                                \
        __builtin_amdgcn_s_setprio(0);                                        \
    }                                                                         \
    float mx = -__builtin_inff();                                             \
    _Pragma("unroll")                                                         \
    for (int j = 0; j < 8; j++) {                                             \
        _Pragma("unroll")                                                     \
        for (int r = 0; r < 4; r++) {                                         \
            float v = p8[j][r] * 0.125f;                                      \
            if (MASK) {                                                       \
                int ka = (KT) * 128 + (j >> 1) * 32 + g * 8 + ((j & 1) << 2) + r; \
                v = (ka > (QLANE)) ? -__builtin_inff() : v;                   \
            }                                                                 \
            p8[j][r] = v;                                                     \
            mx = fmaxf(mx, v);                                                \
        }                                                                     \
    }                                                                         \
    mx = fmaxf(mx, __shfl_xor(mx, 16));                                       \
    mx = fmaxf(mx, __shfl_xor(mx, 32));                                       \
    float mnew = fmaxf(MVAR, mx);                                             \
    float alpha = __expf(MVAR - mnew);                                        \
    MVAR = mnew;                                                              \
    _Pragma("unroll")                                                         \
    for (int r = 0; r < 4; r++) {                                             \
        float ar = __shfl(alpha, g * 4 + r);                                  \
        _Pragma("unroll")                                                     \
        for (int dj = 0; dj < 4; dj++) OACC[dj][r] *= ar;                     \
    }                                                                         \
    float ls = 0.f;                                                           \
    _Pragma("unroll")                                                         \
    for (int j = 0; j < 8; j++)                                               \
        _Pragma("unroll")                                                     \
        for (int r = 0; r < 4; r++) {                                         \
            float e = __expf(p8[j][r] - mnew);                                \
            p8[j][r] = e;                                                     \
            ls += e;                                                          \
        }                                                                     \
    ls += __shfl_xor(ls, 16);                                                 \
    ls += __shfl_xor(ls, 32);                                                 \
    LVAR = LVAR * alpha + ls;                                                 \
    _Pragma("unroll")                                                         \
    for (int ks = 0; ks < 4; ks++) {                                          \
        bf16x8 pf;                                                            \
        _Pragma("unroll")                                                     \
        for (int e = 0; e < 8; e++)                                           \
            pf[e] = (__bf16)p8[2 * ks + (e >> 2)][e & 3];                     \
        bf16x8 vf[4];                                                         \
        _Pragma("unroll")                                                     \
        for (int dj = 0; dj < 4; dj++) {                                      \
            int vrow = dj * 16 + cl;                                          \
            int ch = ks * 4 + g;                                              \
            vf[dj] = *(const bf16x8*)(Vs[BUF] + vrow * 128 + ((ch ^ (vrow & 15)) * 8)); \
        }                                                                     \
        __builtin_amdgcn_s_setprio(1);                                        \
        _Pragma("unroll")                                                     \
        for (int dj = 0; dj < 4; dj++)                                        \
            OACC[dj] = __builtin_amdgcn_mfma_f32_16x16x32_bf16(               \
                pf, vf[dj], OACC[dj], 0, 0, 0);                               \
        __builtin_amdgcn_s_setprio(0);                                        \
    }                                                                         \
} while (0)

__global__ __launch_bounds__(256, 2) void attn_fwd(
        const bhalf* __restrict__ Qb, const bhalf* __restrict__ Kb,
        const bhalf* __restrict__ Vtb, bhalf* __restrict__ Ob) {
    __shared__ bhalf Ks[2][128 * 64];   // [buf][krow][d]  swz f(row)=(row&3)|(((row>>3)&1)<<2)
    __shared__ bhalf Vs[2][64 * 128];   // [buf][d][kcol]  swz row&15

    // XCD-aware swizzle: same-(b,h) blocks land on one XCD (bid%8 = XCD)
    const int bid  = blockIdx.x;              // 0..511
    const int xcd  = bid & 7, slot = bid >> 3;
    const int bx   = slot & 15;               // 0..15
    const int bh   = xcd + 8 * (slot >> 4);   // 0..31
    const int qbA  = 31 - bx;                 // heavy half (nktA = 9..16)
    const int qbB  = bx;                      // light half (nktB = 1..8)

    const int tid = threadIdx.x;
    const int w = tid >> 6, lane = tid & 63;
    const int g = lane >> 4, cl = lane & 15;

    const bhalf* Q  = Qb  + (size_t)bh * L_ * DH_;
    const bhalf* Kp = Kb  + (size_t)bh * L_ * DH_;
    const bhalf* Vt = Vtb + (size_t)bh * DH_ * L_;

    const int q0A = qbA * 64 + w * 16, qlA = q0A + cl;
    const int q0B = qbB * 64 + w * 16, qlB = q0B + cl;

    // Q fragments (B-operand) for both halves, in registers for whole block
    bf16x8 qfA[2], qfB[2];
#pragma unroll
    for (int s = 0; s < 2; s++) {
        qfA[s] = *(const bf16x8*)(Q + (size_t)(q0A + cl) * 64 + s * 32 + g * 8);
        qfB[s] = *(const bf16x8*)(Q + (size_t)(q0B + cl) * 64 + s * 32 + g * 8);
    }

    f32x4 oA[4] = {}, oB[4] = {};
    float mA = -__builtin_inff(), lA = 0.f;
    float mB = -__builtin_inff(), lB = 0.f;

    const int nktA = (qbA >> 1) + 1;
    const int nktB = (qbB >> 1) + 1;
    const int ntot = nktA + nktB;             // == 17 for all blocks

    STAGE(0, 0);
    __syncthreads();

    for (int t = 0; t < ntot; ++t) {
        int cur = t & 1;
        if (t + 1 < ntot) {                   // prefetch next tile
            int tn = t + 1;
            int ktn = (tn < nktA) ? tn : (tn - nktA);
            STAGE(cur ^ 1, ktn);
        }
        if (t < nktA) {
            ATTN_TILE(cur, t, qfA, qlA, mA, lA, oA, (t == nktA - 1));
        } else {
            int kt = t - nktA;
            ATTN_TILE(cur, kt, qfB, qlB, mB, lB, oB, (kt == nktB - 1));
        }
        __syncthreads();   // next buffer staged; current free to overwrite
    }

    // epilogue: divide by denom (+1e-6 per reference), write O [B,L,D]
    const int b = bh >> 4, h = bh & 15;
#pragma unroll
    for (int r = 0; r < 4; r++) {
        float lrA = __shfl(lA, g * 4 + r);
        float lrB = __shfl(lB, g * 4 + r);
        float invA = 1.f / (lrA + 1e-6f);
        float invB = 1.f / (lrB + 1e-6f);
        int qrA = q0A + g * 4 + r, qrB = q0B + g * 4 + r;
#pragma unroll
        for (int dj = 0; dj < 4; dj++) {
            Ob[((size_t)b * L_ + qrA) * D_ + h * 64 + dj * 16 + cl] =
                f2bf(oA[dj][r] * invA);
            Ob[((size_t)b * L_ + qrB) * D_ + h * 64 + dj * 16 + cl] =
                f2bf(oB[dj][r] * invB);
        }
    }
}

// ---------------------------------------------------------------------------
extern "C" void kernel_launch(void* const* d_in, const int* in_sizes, int n_in,
                              void* d_out, int out_size, void* d_ws, size_t ws_size,
                              hipStream_t stream) {
    const void* x     = d_in[0];   // [B,L,D]     f32 or bf16
    const void* Wqkv  = d_in[1];   // [D, 3D]
    const void* bqkv  = d_in[2];   // [3D]
    const void* Wproj = d_in[3];   // [D, D]
    const void* bproj = d_in[4];   // [D]

    char* ws = (char*)d_ws;
    const size_t SZ_FLG = 256;
    const size_t SZ_WQT = (size_t)3 * D_ * D_ * 2;        //  6 MB  Wqkv^T [3D][D]
    const size_t SZ_WPT = (size_t)D_ * D_ * 2;            //  2 MB  Wproj^T [D][D]
    const size_t SZ_X   = (size_t)B_ * L_ * D_ * 2;       //  8 MB  x bf16
    const size_t SZ_BUF = (size_t)B_ * H_ * L_ * DH_ * 2; //  8 MB  each

    int*   flag = (int*)ws;
    bhalf* Wq_t = (bhalf*)(ws + SZ_FLG);
    bhalf* Wp_t = (bhalf*)(ws + SZ_FLG + SZ_WQT);
    bhalf* Xb   = (bhalf*)(ws + SZ_FLG + SZ_WQT + SZ_WPT);
    bhalf* Qbuf = (bhalf*)(ws + SZ_FLG + SZ_WQT + SZ_WPT + SZ_X);
    bhalf* Kbuf = (bhalf*)(ws + SZ_FLG + SZ_WQT + SZ_WPT + SZ_X + SZ_BUF);
    bhalf* Vtbf = (bhalf*)(ws + SZ_FLG + SZ_WQT + SZ_WPT + SZ_X + 2 * SZ_BUF);
    bhalf* Obuf = (bhalf*)(ws + SZ_FLG + SZ_WQT + SZ_WPT + SZ_X + 3 * SZ_BUF);

    const int M = B_ * L_;   // 4096

    // 0. runtime dtype detection from x's bit patterns
    detect_dtype<<<1, 64, 0, stream>>>((const uint32*)x, flag);

    // 1. canonicalize inputs to bf16 workspace
    conv_bf16<<<2048, 256, 0, stream>>>(x, Xb, (B_ * L_ * D_) / 4, flag);
    tr_conv<<<dim3(3 * D_ / 32, D_ / 32), dim3(32, 8), 0, stream>>>(
        Wqkv, Wq_t, D_, 3 * D_, flag);
    tr_conv<<<dim3(D_ / 32, D_ / 32), dim3(32, 8), 0, stream>>>(
        Wproj, Wp_t, D_, D_, flag);

    // 2. QKV projection + scatter to Q,K [B,H,L,DH] and Vt [B,H,DH,L]
    gemm_bt<1><<<dim3(3 * D_ / 128, M / 128), 256, 0, stream>>>(
        Xb, Wq_t, bqkv, nullptr, Qbuf, Kbuf, Vtbf, M, 3 * D_, D_, flag);

    // 3. causal flash attention -> Obuf [B,L,D] bf16
    attn_fwd<<<dim3(512), 256, 0, stream>>>(Qbuf, Kbuf, Vtbf, Obuf);

    // 4. output projection -> d_out (f32 or bf16 per flag)
    gemm_bt<0><<<dim3(D_ / 128, M / 128), 256, 0, stream>>>(
        Obuf, Wp_t, bproj, d_out, nullptr, nullptr, nullptr, M, D_, D_, flag);
}

// Round 6
// 125.009 us; speedup vs baseline: 1.9570x; 1.0727x over previous
//
#include <hip/hip_runtime.h>

// ---------------------------------------------------------------------------
// Fused causal MHA:  out = attn(x@Wqkv+b) @ Wproj + bproj
// B=2, L=2048, D=1024, H=16, DH=64
// Device buffers may be f32 or bf16 -- detected at runtime from x's bit
// patterns; all compute is bf16 MFMA internally.
// Softmax runs in exp2 space: Q is pre-scaled by 0.125*log2(e) in the QKV
// GEMM epilogue, so scores are already log2-domain.
// ---------------------------------------------------------------------------

typedef __bf16 bf16x8 __attribute__((ext_vector_type(8)));
typedef float  f32x4  __attribute__((ext_vector_type(4)));
typedef unsigned short bhalf;
typedef unsigned int   uint32;

#define B_  2
#define L_  2048
#define D_  1024
#define H_  16
#define DH_ 64

#define GPTR(p) ((const __attribute__((address_space(1))) void*)(p))
#define SPTR(p) ((__attribute__((address_space(3))) void*)(p))

static __device__ __forceinline__ float bf2f(bhalf u) {
    union { uint32 u; float f; } x; x.u = ((uint32)u) << 16; return x.f;
}
static __device__ __forceinline__ bhalf f2bf(float f) {
    union { float f; uint32 u; } x; x.f = f;
    uint32 r = x.u + 0x7FFFu + ((x.u >> 16) & 1u);   // RNE
    return (bhalf)(r >> 16);
}

// ---------------------------------------------------------------------------
// dtype detection: x ~ N(0,1). If words are f32, their low 16 bits viewed as
// bf16 have ~uniform-random exponents (garbage); if genuine bf16, exponents
// cluster near 0x7F. flag: 0 = f32 buffers, 1 = bf16 buffers.
// ---------------------------------------------------------------------------
__global__ void detect_dtype(const uint32* __restrict__ xw, int* __restrict__ flag) {
    int t = threadIdx.x;                     // 64 threads
    uint32 w = xw[t];
    uint32 e = (w >> 7) & 0xFFu;             // exponent of low-half bf16
    int g = (e < 0x6Fu || e > 0x84u) ? 1 : 0;  // |v|<2^-16 or |v|>32 => garbage
#pragma unroll
    for (int off = 32; off; off >>= 1) g += __shfl_xor(g, off);
    if (t == 0) *flag = (g > 16) ? 0 : 1;
}

// ---------------------------------------------------------------------------
// convert x (f32 or bf16) -> bf16, 4 elems/thread
// ---------------------------------------------------------------------------
__global__ void conv_bf16(const void* __restrict__ in, bhalf* __restrict__ out,
                          int n4, const int* __restrict__ flag) {
    const bool isb = (*flag != 0);
    for (int i = blockIdx.x * blockDim.x + threadIdx.x; i < n4;
         i += gridDim.x * blockDim.x) {
        if (isb) {
            ((uint2*)out)[i] = ((const uint2*)in)[i];
        } else {
            float4 v = ((const float4*)in)[i];
            uint2 o;
            o.x = (uint32)f2bf(v.x) | ((uint32)f2bf(v.y) << 16);
            o.y = (uint32)f2bf(v.z) | ((uint32)f2bf(v.w) << 16);
            ((uint2*)out)[i] = o;
        }
    }
}

// ---------------------------------------------------------------------------
// transpose + convert: in [R][C] (f32 or bf16) -> out [C][R] bf16
// ---------------------------------------------------------------------------
__global__ void tr_conv(const void* __restrict__ in, bhalf* __restrict__ out,
                        int R, int C, const int* __restrict__ flag) {
    __shared__ bhalf t[32][33];
    const bool isb = (*flag != 0);
    int bx = blockIdx.x, by = blockIdx.y;
    int tx = threadIdx.x, ty = threadIdx.y;   // (32, 8)
#pragma unroll
    for (int i = 0; i < 32; i += 8) {
        size_t idx = (size_t)(by * 32 + ty + i) * C + bx * 32 + tx;
        t[ty + i][tx] = isb ? ((const bhalf*)in)[idx]
                            : f2bf(((const float*)in)[idx]);
    }
    __syncthreads();
#pragma unroll
    for (int i = 0; i < 32; i += 8)
        out[(size_t)(bx * 32 + ty + i) * R + by * 32 + tx] = t[tx][ty + i];
}

// ---------------------------------------------------------------------------
// GEMM  C[M][N] = A[M][K] @ Bt[N][K]^T + bias[N]     (A, Bt are bf16)
// 128x128 tile, BK=32, 256 threads = 4 waves each 64x64.
// Double-buffered LDS, prefetch-next-before-compute; one barrier per k-step.
// Chunk permutation pos = (c + row + (row>>2)) & 3 -> 2-way (free) LDS banks.
// MODE 0: write C row-major (f32 or bf16 per flag) to C0.
// MODE 1: QKV scatter: Q (pre-scaled by 0.125*log2e), K -> [B,H,L,DH] bf16,
//         V -> Vt [B,H,DH,L] bf16.
// ---------------------------------------------------------------------------

#define GSTAGE(BUF, KK) do {                                                  \
    int kko = (KK);                                                           \
    _Pragma("unroll")                                                         \
    for (int r = 0; r < 2; r++) {                                             \
        int c = r * 256 + tid;                                                \
        int row = c >> 2, p = c & 3;                                          \
        int gch = (p - row - (row >> 2)) & 3;                                 \
        __builtin_amdgcn_global_load_lds(                                     \
            GPTR(a0 + (size_t)row * K + kko + gch * 8),                       \
            SPTR(As[BUF] + (r * 256 + w * 64) * 8), 16, 0, 0);                \
        __builtin_amdgcn_global_load_lds(                                     \
            GPTR(b0 + (size_t)row * K + kko + gch * 8),                       \
            SPTR(Bs[BUF] + (r * 256 + w * 64) * 8), 16, 0, 0);                \
    }                                                                         \
} while (0)

template <int MODE>
__global__ __launch_bounds__(256) void gemm_bt(
        const bhalf* __restrict__ A, const bhalf* __restrict__ Bt,
        const void* __restrict__ bias,
        void* __restrict__ C0, bhalf* __restrict__ Qb,
        bhalf* __restrict__ Kb, bhalf* __restrict__ Vtb,
        int M, int N, int K, const int* __restrict__ flag) {
    __shared__ bhalf As[2][128 * 32];
    __shared__ bhalf Bs[2][128 * 32];
    const bool isb = (*flag != 0);
    const int tid  = threadIdx.x;
    const int w    = tid >> 6, lane = tid & 63;
    const int g    = lane >> 4, cl = lane & 15;
    const int m0   = blockIdx.y * 128, n0 = blockIdx.x * 128;
    const int wr   = (w >> 1) * 64, wc = (w & 1) * 64;

    f32x4 acc[4][4] = {};

    const bhalf* a0 = A  + (size_t)m0 * K;
    const bhalf* b0 = Bt + (size_t)n0 * K;

    GSTAGE(0, 0);
    __syncthreads();

    const int nk = K >> 5;
    for (int t = 0; t < nk; ++t) {
        int cur = t & 1;
        if (t + 1 < nk) GSTAGE(cur ^ 1, (t + 1) << 5);   // prefetch next tile

        bf16x8 af[4], bf4[4];
#pragma unroll
        for (int i = 0; i < 4; i++) {
            int ra = wr + i * 16 + cl;
            af[i]  = *(const bf16x8*)(As[cur] + ra * 32 +
                                      (((g + ra + (ra >> 2)) & 3) * 8));
            int rb = wc + i * 16 + cl;
            bf4[i] = *(const bf16x8*)(Bs[cur] + rb * 32 +
                                      (((g + rb + (rb >> 2)) & 3) * 8));
        }
        __builtin_amdgcn_s_setprio(1);
#pragma unroll
        for (int i = 0; i < 4; i++)
#pragma unroll
            for (int j = 0; j < 4; j++)
                acc[i][j] = __builtin_amdgcn_mfma_f32_16x16x32_bf16(
                    af[i], bf4[j], acc[i][j], 0, 0, 0);
        __builtin_amdgcn_s_setprio(0);

        __syncthreads();   // next buffer staged; cur free to overwrite
    }

    // epilogue: C/D layout col = lane&15, row = (lane>>4)*4 + reg
#pragma unroll
    for (int i = 0; i < 4; i++) {
#pragma unroll
        for (int j = 0; j < 4; j++) {
            int nn = n0 + wc + j * 16 + cl;
            float bv = isb ? bf2f(((const bhalf*)bias)[nn])
                           : ((const float*)bias)[nn];
#pragma unroll
            for (int r = 0; r < 4; r++) {
                int mm = m0 + wr + i * 16 + g * 4 + r;
                float v = acc[i][j][r] + bv;
                if (MODE == 0) {
                    if (isb) ((bhalf*)C0)[(size_t)mm * N + nn] = f2bf(v);
                    else     ((float*)C0)[(size_t)mm * N + nn] = v;
                } else {
                    int b = mm >> 11, l = mm & 2047;
                    int three = nn >> 10, rem = nn & 1023;
                    int h = rem >> 6, dh = rem & 63;
                    size_t bh = (size_t)(b * 16 + h);
                    if (three == 0) {
                        // fold SCALE * log2(e) into Q (softmax in exp2 space)
                        Qb[(bh * 2048 + l) * 64 + dh] = f2bf(v * 0.18033688f);
                    } else if (three == 1) {
                        Kb [(bh * 2048 + l) * 64 + dh] = f2bf(v);
                    } else {
                        Vtb[(bh * 64 + dh) * 2048 + l] = f2bf(v);
                    }
                }
            }
        }
    }
}

// ---------------------------------------------------------------------------
// Causal flash attention, swapped-QK^T / in-register exp2-space softmax.
// 512 blocks x 256 threads (4 waves). Each block handles TWO 64-row q-tiles
// (qbA = 31-bx heavy, qbB = bx light). B's k-range is a SUBSET of A's, so we
// stage only nktA tiles and process B while each tile is resident:
// staging traffic and barriers drop ~26%, compute stays balanced (17 tile-
// computes per block everywhere). K/V double-buffered with prefetch.
// Softmax: scores arrive pre-scaled by 0.125*log2e -> exp2 directly; tree
// reductions (4 chains); defer-max (skip rescale while max grows <= 2^8).
// Q [B,H,L,DH], K [B,H,L,DH], Vt [B,H,DH,L]; O -> [B,L,D] bf16.
// ---------------------------------------------------------------------------

// stage K/V tile kt into LDS buffer BUF (pre-swizzled global source)
#define STAGE(BUF, KT) do {                                                   \
    int ktv = (KT);                                                           \
    _Pragma("unroll")                                                         \
    for (int r = 0; r < 4; r++) {                                             \
        int c = r * 256 + tid;                                                \
        int row = c >> 3, p = c & 7;                                          \
        int fsw = (row & 3) | (((row >> 3) & 1) << 2);                        \
        __builtin_amdgcn_global_load_lds(                                     \
            GPTR(Kp + (size_t)(ktv * 128 + row) * 64 + (p ^ fsw) * 8),        \
            SPTR(Ks[BUF] + (r * 256 + w * 64) * 8), 16, 0, 0);                \
    }                                                                         \
    _Pragma("unroll")                                                         \
    for (int r = 0; r < 4; r++) {                                             \
        int c = r * 256 + tid;                                                \
        int row = c >> 4, p = c & 15;                                         \
        __builtin_amdgcn_global_load_lds(                                     \
            GPTR(Vt + (size_t)row * L_ + ktv * 128 + (p ^ (row & 15)) * 8),   \
            SPTR(Vs[BUF] + (r * 256 + w * 64) * 8), 16, 0, 0);                \
    }                                                                         \
} while (0)

// one k-tile: S^T = K@Q^T -> exp2-space online softmax -> O += P@Vt^T
#define ATTN_TILE(BUF, KT, QF, QLANE, MVAR, LVAR, OACC, MASK) do {            \
    f32x4 p8[8] = {};                                                         \
    _Pragma("unroll")                                                         \
    for (int s = 0; s < 2; s++) {                                             \
        bf16x8 kf[8];                                                         \
        _Pragma("unroll")                                                     \
        for (int j = 0; j < 8; j++) {                                         \
            int row = (j >> 1) * 32 + (cl >> 2) * 8 + (j & 1) * 4 + (cl & 3); \
            int fsw = (row & 3) | (((row >> 3) & 1) << 2);                    \
            int ch = s * 4 + g;                                               \
            kf[j] = *(const bf16x8*)(Ks[BUF] + row * 64 + ((ch ^ fsw) * 8));  \
        }                                                                     \
        __builtin_amdgcn_s_setprio(1);                                        \
        _Pragma("unroll")                                                     \
        for (int j = 0; j < 8; j++)                                           \
            p8[j] = __builtin_amdgcn_mfma_f32_16x16x32_bf16(                  \
                kf[j], QF[s], p8[j], 0, 0, 0);                                \
        __builtin_amdgcn_s_setprio(0);                                        \
    }                                                                         \
    float mx0 = -__builtin_inff(), mx1 = -__builtin_inff();                   \
    float mx2 = -__builtin_inff(), mx3 = -__builtin_inff();                   \
    _Pragma("unroll")                                                         \
    for (int j = 0; j < 8; j++) {                                             \
        float v0 = p8[j][0], v1 = p8[j][1], v2 = p8[j][2], v3 = p8[j][3];     \
        if (MASK) {                                                           \
            int ka = (KT) * 128 + (j >> 1) * 32 + g * 8 + ((j & 1) << 2);     \
            v0 = (ka + 0 > (QLANE)) ? -__builtin_inff() : v0;                 \
            v1 = (ka + 1 > (QLANE)) ? -__builtin_inff() : v1;                 \
            v2 = (ka + 2 > (QLANE)) ? -__builtin_inff() : v2;                 \
            v3 = (ka + 3 > (QLANE)) ? -__builtin_inff() : v3;                 \
            p8[j][0] = v0; p8[j][1] = v1; p8[j][2] = v2; p8[j][3] = v3;       \
        }                                                                     \
        mx0 = fmaxf(mx0, v0); mx1 = fmaxf(mx1, v1);                           \
        mx2 = fmaxf(mx2, v2); mx3 = fmaxf(mx3, v3);                           \
    }                                                                         \
    float mx = fmaxf(fmaxf(mx0, mx1), fmaxf(mx2, mx3));                       \
    mx = fmaxf(mx, __shfl_xor(mx, 16));                                       \
    mx = fmaxf(mx, __shfl_xor(mx, 32));                                       \
    if (!__all(mx - MVAR <= 8.f)) {      /* defer-max: rescale only on growth */ \
        float mnew = fmaxf(MVAR, mx);                                         \
        float alpha = __builtin_amdgcn_exp2f(MVAR - mnew);                    \
        MVAR = mnew;                                                          \
        LVAR *= alpha;                                                        \
        _Pragma("unroll")                                                     \
        for (int r = 0; r < 4; r++) {                                         \
            float ar = __shfl(alpha, g * 4 + r);                              \
            _Pragma("unroll")                                                 \
            for (int dj = 0; dj < 4; dj++) OACC[dj][r] *= ar;                 \
        }                                                                     \
    }                                                                         \
    float s0 = 0.f, s1 = 0.f, s2 = 0.f, s3 = 0.f;                             \
    _Pragma("unroll")                                                         \
    for (int j = 0; j < 8; j++) {                                             \
        float e0 = __builtin_amdgcn_exp2f(p8[j][0] - MVAR);                   \
        float e1 = __builtin_amdgcn_exp2f(p8[j][1] - MVAR);                   \
        float e2 = __builtin_amdgcn_exp2f(p8[j][2] - MVAR);                   \
        float e3 = __builtin_amdgcn_exp2f(p8[j][3] - MVAR);                   \
        p8[j][0] = e0; p8[j][1] = e1; p8[j][2] = e2; p8[j][3] = e3;           \
        s0 += e0; s1 += e1; s2 += e2; s3 += e3;                               \
    }                                                                         \
    float ls = (s0 + s1) + (s2 + s3);                                         \
    ls += __shfl_xor(ls, 16);                                                 \
    ls += __shfl_xor(ls, 32);                                                 \
    LVAR += ls;                                                               \
    _Pragma("unroll")                                                         \
    for (int ks = 0; ks < 4; ks++) {                                          \
        bf16x8 pf;                                                            \
        _Pragma("unroll")                                                     \
        for (int e = 0; e < 8; e++)                                           \
            pf[e] = (__bf16)p8[2 * ks + (e >> 2)][e & 3];                     \
        bf16x8 vf[4];                                                         \
        _Pragma("unroll")                                                     \
        for (int dj = 0; dj < 4; dj++) {                                      \
            int vrow = dj * 16 + cl;                                          \
            int ch = ks * 4 + g;                                              \
            vf[dj] = *(const bf16x8*)(Vs[BUF] + vrow * 128 + ((ch ^ (vrow & 15)) * 8)); \
        }                                                                     \
        __builtin_amdgcn_s_setprio(1);                                        \
        _Pragma("unroll")                                                     \
        for (int dj = 0; dj < 4; dj++)                                        \
            OACC[dj] = __builtin_amdgcn_mfma_f32_16x16x32_bf16(               \
                pf, vf[dj], OACC[dj], 0, 0, 0);                               \
        __builtin_amdgcn_s_setprio(0);                                        \
    }                                                                         \
} while (0)

__global__ __launch_bounds__(256, 2) void attn_fwd(
        const bhalf* __restrict__ Qb, const bhalf* __restrict__ Kb,
        const bhalf* __restrict__ Vtb, bhalf* __restrict__ Ob) {
    __shared__ bhalf Ks[2][128 * 64];   // [buf][krow][d]  swz f(row)=(row&3)|(((row>>3)&1)<<2)
    __shared__ bhalf Vs[2][64 * 128];   // [buf][d][kcol]  swz row&15

    // XCD-aware swizzle: same-(b,h) blocks land on one XCD (bid%8 = XCD)
    const int bid  = blockIdx.x;              // 0..511
    const int xcd  = bid & 7, slot = bid >> 3;
    const int bx   = slot & 15;               // 0..15
    const int bh   = xcd + 8 * (slot >> 4);   // 0..31
    const int qbA  = 31 - bx;                 // heavy half (nktA = 9..16)
    const int qbB  = bx;                      // light half (nktB = 1..8), kt-range subset of A

    const int tid = threadIdx.x;
    const int w = tid >> 6, lane = tid & 63;
    const int g = lane >> 4, cl = lane & 15;

    const bhalf* Q  = Qb  + (size_t)bh * L_ * DH_;
    const bhalf* Kp = Kb  + (size_t)bh * L_ * DH_;
    const bhalf* Vt = Vtb + (size_t)bh * DH_ * L_;

    const int q0A = qbA * 64 + w * 16, qlA = q0A + cl;
    const int q0B = qbB * 64 + w * 16, qlB = q0B + cl;

    // Q fragments (B-operand) for both halves, in registers for whole block
    bf16x8 qfA[2], qfB[2];
#pragma unroll
    for (int s = 0; s < 2; s++) {
        qfA[s] = *(const bf16x8*)(Q + (size_t)(q0A + cl) * 64 + s * 32 + g * 8);
        qfB[s] = *(const bf16x8*)(Q + (size_t)(q0B + cl) * 64 + s * 32 + g * 8);
    }

    f32x4 oA[4] = {}, oB[4] = {};
    float mA = -__builtin_inff(), lA = 0.f;
    float mB = -__builtin_inff(), lB = 0.f;

    const int nktA = (qbA >> 1) + 1;          // 9..16
    const int nktB = (qbB >> 1) + 1;          // 1..8   (nktB < nktA always)

    STAGE(0, 0);
    __syncthreads();

    for (int kt = 0; kt < nktA; ++kt) {
        int cur = kt & 1;
        if (kt + 1 < nktA) STAGE(cur ^ 1, kt + 1);   // prefetch next tile
        if (kt < nktB) {
            ATTN_TILE(cur, kt, qfB, qlB, mB, lB, oB, (kt == nktB - 1));
        }
        ATTN_TILE(cur, kt, qfA, qlA, mA, lA, oA, (kt == nktA - 1));
        __syncthreads();   // next buffer staged; current free to overwrite
    }

    // epilogue: divide by denom (+1e-6 per reference), write O [B,L,D]
    const int b = bh >> 4, h = bh & 15;
#pragma unroll
    for (int r = 0; r < 4; r++) {
        float lrA = __shfl(lA, g * 4 + r);
        float lrB = __shfl(lB, g * 4 + r);
        float invA = 1.f / (lrA + 1e-6f);
        float invB = 1.f / (lrB + 1e-6f);
        int qrA = q0A + g * 4 + r, qrB = q0B + g * 4 + r;
#pragma unroll
        for (int dj = 0; dj < 4; dj++) {
            Ob[((size_t)b * L_ + qrA) * D_ + h * 64 + dj * 16 + cl] =
                f2bf(oA[dj][r] * invA);
            Ob[((size_t)b * L_ + qrB) * D_ + h * 64 + dj * 16 + cl] =
                f2bf(oB[dj][r] * invB);
        }
    }
}

// ---------------------------------------------------------------------------
extern "C" void kernel_launch(void* const* d_in, const int* in_sizes, int n_in,
                              void* d_out, int out_size, void* d_ws, size_t ws_size,
                              hipStream_t stream) {
    const void* x     = d_in[0];   // [B,L,D]     f32 or bf16
    const void* Wqkv  = d_in[1];   // [D, 3D]
    const void* bqkv  = d_in[2];   // [3D]
    const void* Wproj = d_in[3];   // [D, D]
    const void* bproj = d_in[4];   // [D]

    char* ws = (char*)d_ws;
    const size_t SZ_FLG = 256;
    const size_t SZ_WQT = (size_t)3 * D_ * D_ * 2;        //  6 MB  Wqkv^T [3D][D]
    const size_t SZ_WPT = (size_t)D_ * D_ * 2;            //  2 MB  Wproj^T [D][D]
    const size_t SZ_X   = (size_t)B_ * L_ * D_ * 2;       //  8 MB  x bf16
    const size_t SZ_BUF = (size_t)B_ * H_ * L_ * DH_ * 2; //  8 MB  each

    int*   flag = (int*)ws;
    bhalf* Wq_t = (bhalf*)(ws + SZ_FLG);
    bhalf* Wp_t = (bhalf*)(ws + SZ_FLG + SZ_WQT);
    bhalf* Xb   = (bhalf*)(ws + SZ_FLG + SZ_WQT + SZ_WPT);
    bhalf* Qbuf = (bhalf*)(ws + SZ_FLG + SZ_WQT + SZ_WPT + SZ_X);
    bhalf* Kbuf = (bhalf*)(ws + SZ_FLG + SZ_WQT + SZ_WPT + SZ_X + SZ_BUF);
    bhalf* Vtbf = (bhalf*)(ws + SZ_FLG + SZ_WQT + SZ_WPT + SZ_X + 2 * SZ_BUF);
    bhalf* Obuf = (bhalf*)(ws + SZ_FLG + SZ_WQT + SZ_WPT + SZ_X + 3 * SZ_BUF);

    const int M = B_ * L_;   // 4096

    // 0. runtime dtype detection from x's bit patterns
    detect_dtype<<<1, 64, 0, stream>>>((const uint32*)x, flag);

    // 1. canonicalize inputs to bf16 workspace
    conv_bf16<<<2048, 256, 0, stream>>>(x, Xb, (B_ * L_ * D_) / 4, flag);
    tr_conv<<<dim3(3 * D_ / 32, D_ / 32), dim3(32, 8), 0, stream>>>(
        Wqkv, Wq_t, D_, 3 * D_, flag);
    tr_conv<<<dim3(D_ / 32, D_ / 32), dim3(32, 8), 0, stream>>>(
        Wproj, Wp_t, D_, D_, flag);

    // 2. QKV projection + scatter to Q (pre-scaled), K [B,H,L,DH], Vt [B,H,DH,L]
    gemm_bt<1><<<dim3(3 * D_ / 128, M / 128), 256, 0, stream>>>(
        Xb, Wq_t, bqkv, nullptr, Qbuf, Kbuf, Vtbf, M, 3 * D_, D_, flag);

    // 3. causal flash attention -> Obuf [B,L,D] bf16
    attn_fwd<<<dim3(512), 256, 0, stream>>>(Qbuf, Kbuf, Vtbf, Obuf);

    // 4. output projection -> d_out (f32 or bf16 per flag)
    gemm_bt<0><<<dim3(D_ / 128, M / 128), 256, 0, stream>>>(
        Obuf, Wp_t, bproj, d_out, nullptr, nullptr, nullptr, M, D_, D_, flag);
}